// Round 1
// baseline (2316.637 us; speedup 1.0000x reference)
//
#include <hip/hip_runtime.h>
#include <math.h>

typedef __attribute__((ext_vector_type(8))) short short8;
typedef __attribute__((ext_vector_type(4))) float floatx4;

#define M_TOT 200704            // 64*56*56 token rows
#define SCALE_Q 0.17677669529663687f   // 32^-0.5

__device__ __forceinline__ float u2f(unsigned int u){ return __uint_as_float(u << 16); }
__device__ __forceinline__ unsigned short f2u(float f){
  unsigned int x = __float_as_uint(f);
  x += 0x7fffu + ((x >> 16) & 1u);       // RNE f32->bf16
  return (unsigned short)(x >> 16);
}

// window-layout row m -> spatial row of x (shift+partition gather; same map is the
// reverse+unshift scatter destination: both are +3 cyclic in each axis)
__device__ __forceinline__ int win_to_x(int m){
  int bb = m / 3136; int rem = m - bb*3136;
  int w = rem / 49, n = rem - w*49;
  int wh = w >> 3, ww = w & 7;
  int i = n / 7, j = n - i*7;
  int p = wh*7 + i + 3; if (p >= 56) p -= 56;
  int q = ww*7 + j + 3; if (q >= 56) q -= 56;
  return bb*3136 + p*56 + q;
}

// ---------------- prep: f32 W[K][N] -> bf16 Wt[N][K]  ----------------
__global__ void conv_wt(const float* __restrict__ in, unsigned short* __restrict__ out,
                        int K, int N){
  int t = blockIdx.x*256 + threadIdx.x;
  if (t < K*N){ int k = t / N, n = t - k*N; out[n*K + k] = f2u(in[t]); }
}
// ---------------- prep: row gather/scatter map ----------------
__global__ void rowmap_k(int* __restrict__ map){
  int t = blockIdx.x*256 + threadIdx.x;
  if (t < M_TOT) map[t] = win_to_x(t);
}

// ---------------- MFMA GEMM, 64 rows x 192 cols per block ----------------
// A staged once into LDS (fused LN, single pass); B fragments read DIRECTLY
// from global pre-transposed bf16 weights (L2-resident, contiguous 16B/lane).
// LNMODE 0: none (A bf16 scratch, stride astride)
//        1: LN + gather via rowmap (A = x, f32, stride 192)
//        2: LN, linear global rows (A = out, f32, stride 192)
// EPI 0: +bias, scale cols<192 (QKV)    -> bf16 scratch, stride ostride
// EPI 1: +bias, scatter via rowmap + residual res=x (f32) -> d_out f32
// EPI 2: +bias, exact GELU              -> bf16 scratch, stride ostride
// EPI 3: +bias, residual res=out (in-place, f32)          -> d_out f32
template<int KTOT, int LNMODE, int EPI>
__global__ __launch_bounds__(256, 4) void gemm_kernel(
    const void* __restrict__ A, int astride, long row0g,
    const unsigned short* __restrict__ Wt,     // [nW][KTOT] bf16
    const float* __restrict__ lng, const float* __restrict__ lnb,
    const float* __restrict__ bias, const float* __restrict__ res,
    void* __restrict__ outp, int ostride, const int* __restrict__ rowmap){
  __shared__ __align__(16) unsigned short As[64*200];   // 64 rows x 192 (pad->200)
  int tid = threadIdx.x;
  // XCD-bijective swizzle (m204 formula): virtual order is row-major (by,bx),
  // each XCD gets a contiguous chunk -> the gx col-blocks sharing an A tile
  // run back-to-back on ONE XCD, so A is fetched once into that XCD's L2.
  int gx = gridDim.x;
  int nwg = gx * gridDim.y;
  int orig = blockIdx.y * gx + blockIdx.x;     // HW dispatch order (x fastest)
  int qc = nwg >> 3, rc = nwg & 7;
  int xcd = orig & 7, idxk = orig >> 3;
  int wgid = (xcd < rc ? xcd*(qc+1) : rc*(qc+1) + (xcd-rc)*qc) + idxk;
  int bx = wgid % gx, by = wgid / gx;
  int n0 = bx * 192;
  long lrow0 = (long)by * 64;                  // local (slab) row base
  int lane = tid & 63, wv = tid >> 6;
  int quad = lane >> 4, l16 = lane & 15;

  if constexpr (LNMODE != 0){
    // single-pass staging: each thread owns a 48-col row segment; stats
    // accumulate in registers during the load, 2-shuffle reduce over the
    // 4 lanes of the row, normalize+convert+store once (no LDS re-read).
    int rr = tid >> 2, sub = tid & 3;
    long srow = (LNMODE == 1) ? (long)rowmap[row0g + lrow0 + rr] : (row0g + lrow0 + rr);
    const float* rp = (const float*)A + srow*192 + sub*48;
    float va[48];
    float s = 0.f, q2 = 0.f;
    #pragma unroll
    for (int i = 0; i < 12; ++i){
      float4 f = *(const float4*)(rp + i*4);
      va[i*4+0] = f.x; va[i*4+1] = f.y; va[i*4+2] = f.z; va[i*4+3] = f.w;
      s += (f.x + f.y) + (f.z + f.w);
      q2 = fmaf(f.x, f.x, q2); q2 = fmaf(f.y, f.y, q2);
      q2 = fmaf(f.z, f.z, q2); q2 = fmaf(f.w, f.w, q2);
    }
    s  += __shfl_xor(s, 1);  q2 += __shfl_xor(q2, 1);
    s  += __shfl_xor(s, 2);  q2 += __shfl_xor(q2, 2);
    float mean = s*(1.f/192.f);
    float rs = rsqrtf(q2*(1.f/192.f) - mean*mean + 1e-5f);
    float mrs = mean * rs;
    unsigned short* dst = As + rr*200 + sub*48;
    #pragma unroll
    for (int i = 0; i < 12; ++i){
      float4 g4 = *(const float4*)(lng + sub*48 + i*4);
      float4 b4 = *(const float4*)(lnb + sub*48 + i*4);
      ushort4 o;
      o.x = f2u(fmaf(fmaf(va[i*4+0], rs, -mrs), g4.x, b4.x));
      o.y = f2u(fmaf(fmaf(va[i*4+1], rs, -mrs), g4.y, b4.y));
      o.z = f2u(fmaf(fmaf(va[i*4+2], rs, -mrs), g4.z, b4.z));
      o.w = f2u(fmaf(fmaf(va[i*4+3], rs, -mrs), g4.w, b4.w));
      *(ushort4*)(dst + i*4) = o;
    }
    __syncthreads();
  }

  floatx4 acc[12];
  #pragma unroll
  for (int i = 0; i < 12; ++i) acc[i] = (floatx4){0.f,0.f,0.f,0.f};
  constexpr int NK = KTOT/192;
  for (int kc = 0; kc < NK; ++kc){
    if constexpr (LNMODE == 0){
      if (kc) __syncthreads();
      #pragma unroll
      for (int it = 0; it < 6; ++it){      // 1536 16B-chunks / 256 threads
        int idx = tid + it*256;
        int rr2 = idx / 24, c16 = idx - rr2*24;
        long asrc = (lrow0 + rr2) * (long)astride + kc*192;
        *(uint4*)(As + rr2*200 + c16*8) = *(const uint4*)((const unsigned short*)A + asrc + c16*8);
      }
      __syncthreads();
    }
    // B fragments straight from global: row n0+nt*16+l16, 16B contiguous.
    const unsigned short* wl = Wt + (long)(n0 + l16)*KTOT + kc*192 + quad*8;
    #pragma unroll
    for (int kk = 0; kk < 6; ++kk){
      short8 af = *(const short8*)(As + (wv*16 + l16)*200 + kk*32 + quad*8);
      #pragma unroll
      for (int nt = 0; nt < 12; ++nt){
        short8 bf = *(const short8*)(wl + nt*16*KTOT + kk*32);
        acc[nt] = __builtin_amdgcn_mfma_f32_16x16x32_bf16(af, bf, acc[nt], 0, 0, 0);
      }
    }
  }
  // epilogue: D row = quad*4+reg, col = lane&15 (verified gfx950 C/D mapping)
  #pragma unroll
  for (int r2 = 0; r2 < 4; ++r2){
    long lm = lrow0 + wv*16 + quad*4 + r2;
    long drow = 0;
    if (EPI == 1) drow = rowmap[row0g + lm];
    if (EPI == 3) drow = row0g + lm;
    #pragma unroll
    for (int nt = 0; nt < 12; ++nt){
      int col = n0 + nt*16 + l16;
      float v = acc[nt][r2] + bias[col];
      if (EPI == 0){
        if (col < 192) v *= SCALE_Q;
        ((unsigned short*)outp)[lm*(long)ostride + col] = f2u(v);
      } else if (EPI == 1){
        v += res[drow*192 + col];
        ((float*)outp)[drow*192 + col] = v;
      } else if (EPI == 2){
        v = 0.5f*v*(1.0f + erff(v*0.70710678118654752f));
        ((unsigned short*)outp)[lm*(long)ostride + col] = f2u(v);
      } else {
        v += res[drow*192 + col];
        ((float*)outp)[drow*192 + col] = v;
      }
    }
  }
}

// ---------------- window attention: one wave per (window, head), in-place on bf16 qkv ----
__global__ __launch_bounds__(64) void attn_kernel(unsigned short* __restrict__ qkv,
    const float* __restrict__ rpb, long win0g){
  __shared__ float Kf[49*32];
  __shared__ float Vf[49*32];
  __shared__ float biasl[169];
  __shared__ int labs[49];
  int bid = blockIdx.x;
  int wb = bid / 6, head = bid - wb*6;   // wb = local window in slab
  int t = threadIdx.x;
  long base = (long)wb * 49 * 576;
  for (int idx = t; idx < 784; idx += 64){   // 49 rows x 16 bf16-pairs
    int j = idx >> 4, k2 = (idx & 15)*2;
    unsigned int ku = *(const unsigned int*)(qkv + base + j*576 + 192 + head*32 + k2);
    Kf[j*32 + k2] = u2f(ku); Kf[j*32 + k2 + 1] = __uint_as_float(ku & 0xffff0000u);
    unsigned int vu = *(const unsigned int*)(qkv + base + j*576 + 384 + head*32 + k2);
    Vf[j*32 + k2] = u2f(vu); Vf[j*32 + k2 + 1] = __uint_as_float(vu & 0xffff0000u);
  }
  for (int idx = t; idx < 169; idx += 64) biasl[idx] = rpb[idx*6 + head];
  if (t < 49){
    int w = (int)((win0g + wb) & 63);     // window index within its image
    int wh = w >> 3, ww = w & 7;
    int i = t / 7, j = t - i*7;
    int p = wh*7 + i, q = ww*7 + j;       // position in shifted frame
    int fp = (p < 49) ? 0 : ((p < 53) ? 1 : 2);
    int fq = (q < 49) ? 0 : ((q < 53) ? 1 : 2);
    labs[t] = fp*3 + fq;
  }
  __syncthreads();
  if (t >= 49) return;
  float qv[32];
  {
    const uint4* qp = (const uint4*)(qkv + base + (long)t*576 + head*32);
    #pragma unroll
    for (int z = 0; z < 4; ++z){
      uint4 u = qp[z];
      qv[z*8+0]=u2f(u.x); qv[z*8+1]=__uint_as_float(u.x & 0xffff0000u);
      qv[z*8+2]=u2f(u.y); qv[z*8+3]=__uint_as_float(u.y & 0xffff0000u);
      qv[z*8+4]=u2f(u.z); qv[z*8+5]=__uint_as_float(u.z & 0xffff0000u);
      qv[z*8+6]=u2f(u.w); qv[z*8+7]=__uint_as_float(u.w & 0xffff0000u);
    }
  }
  int yi = t / 7, xi = t - yi*7;
  int labi = labs[t];
  float s[49];
  #pragma unroll
  for (int yj = 0; yj < 7; ++yj){
    #pragma unroll
    for (int xj = 0; xj < 7; ++xj){
      int j = yj*7 + xj;
      const float* kr = Kf + j*32;
      float a0=0.f,a1=0.f,a2=0.f,a3=0.f;
      #pragma unroll
      for (int k = 0; k < 32; k += 4){
        a0 = fmaf(qv[k],   kr[k],   a0);
        a1 = fmaf(qv[k+1], kr[k+1], a1);
        a2 = fmaf(qv[k+2], kr[k+2], a2);
        a3 = fmaf(qv[k+3], kr[k+3], a3);
      }
      float sv = (a0+a1)+(a2+a3);
      sv += biasl[(yi - yj + 6)*13 + (xi - xj + 6)];
      sv += (labs[j] == labi) ? 0.0f : -100.0f;
      s[j] = sv;
    }
  }
  float mx = s[0];
  #pragma unroll
  for (int j = 1; j < 49; ++j) mx = fmaxf(mx, s[j]);
  float l = 0.f;
  #pragma unroll
  for (int j = 0; j < 49; ++j){ float e = __expf(s[j]-mx); s[j] = e; l += e; }
  float inv = 1.0f / l;
  float o[32];
  #pragma unroll
  for (int k = 0; k < 32; ++k) o[k] = 0.f;
  #pragma unroll
  for (int j = 0; j < 49; ++j){
    float pj = s[j];
    const float* vr = Vf + j*32;
    #pragma unroll
    for (int k = 0; k < 32; ++k) o[k] = fmaf(pj, vr[k], o[k]);
  }
  // write over own q-slice (block-local, race-free)
  unsigned short* op = qkv + base + (long)t*576 + head*32;
  uint4 ov[4];
  unsigned int* ow = (unsigned int*)ov;
  #pragma unroll
  for (int k2 = 0; k2 < 16; ++k2){
    ow[k2] = (unsigned int)f2u(o[2*k2]*inv) | ((unsigned int)f2u(o[2*k2+1]*inv) << 16);
  }
  uint4* o4 = (uint4*)op;
  #pragma unroll
  for (int z = 0; z < 4; ++z) o4[z] = ov[z];
}

extern "C" void kernel_launch(void* const* d_in, const int* in_sizes, int n_in,
                              void* d_out, int out_size, void* d_ws, size_t ws_size,
                              hipStream_t stream){
  const float* x     = (const float*)d_in[0];
  const float* ln1_g = (const float*)d_in[1];
  const float* ln1_b = (const float*)d_in[2];
  const float* qkv_w = (const float*)d_in[3];
  const float* qkv_b = (const float*)d_in[4];
  const float* proj_w= (const float*)d_in[5];
  const float* proj_b= (const float*)d_in[6];
  const float* rpb   = (const float*)d_in[7];
  const float* ln2_g = (const float*)d_in[8];
  const float* ln2_b = (const float*)d_in[9];
  const float* w1    = (const float*)d_in[10];
  const float* b1    = (const float*)d_in[11];
  const float* w2    = (const float*)d_in[12];
  const float* b2    = (const float*)d_in[13];
  float* out = (float*)d_out;

  // ws layout: bf16 transposed weights | rowmap | activation scratch
  unsigned short* wt_qkv  = (unsigned short*)d_ws;        // 576 x 192
  unsigned short* wt_proj = wt_qkv  + 576*192;            // 192 x 192
  unsigned short* wt_m1   = wt_proj + 192*192;            // 768 x 192
  unsigned short* wt_m2   = wt_m1   + 768*192;            // 192 x 768
  int* rowmap = (int*)(wt_m2 + 192*768);                  // M_TOT ints
  unsigned short* buf = (unsigned short*)(rowmap + M_TOT);
  size_t ovh = (size_t)(576*192 + 192*192 + 768*192 + 192*768)*2 + (size_t)M_TOT*4;
  size_t bufb = ws_size > ovh ? ws_size - ovh : 0;

  // --- slab sizing (depends only on constant ws_size -> identical every call) ---
  int da = 64;
  while (da > 1 && (size_t)3136*(size_t)da*1152ULL > bufb) da >>= 1;
  long Sa = 3136L*da;             // attention slab rows (whole images); qkv bytes = Sa*1152
  int nA = 64/da;
  static const long smlist[] = {200704,100352,50176,25088,12544,6272,3136,1792,1024,512,448,256,128,64};
  long Sm = 64;
  for (int i = 0; i < 14; ++i) if ((size_t)smlist[i]*1536ULL <= bufb){ Sm = smlist[i]; break; }
  int nM = (int)(M_TOT / Sm);

  // ---- prep: weights -> bf16 transposed; row gather map ----
  conv_wt<<<(192*576+255)/256, 256, 0, stream>>>(qkv_w, wt_qkv, 192, 576);
  conv_wt<<<(192*192+255)/256, 256, 0, stream>>>(proj_w, wt_proj, 192, 192);
  conv_wt<<<(192*768+255)/256, 256, 0, stream>>>(w1, wt_m1, 192, 768);
  conv_wt<<<(768*192+255)/256, 256, 0, stream>>>(w2, wt_m2, 768, 192);
  rowmap_k<<<(M_TOT+255)/256, 256, 0, stream>>>(rowmap);

  // ---- attention branch: x -> out (= x + attn(ln1(x))) ----
  for (int s = 0; s < nA; ++s){
    long r0 = (long)s*Sa;
    gemm_kernel<192,1,0><<<dim3(3, Sa/64), 256, 0, stream>>>(
        x, 192, r0, wt_qkv, ln1_g, ln1_b, qkv_b, nullptr, buf, 576, rowmap);
    attn_kernel<<<(int)(Sa/49)*6, 64, 0, stream>>>(buf, rpb, r0/49);
    gemm_kernel<192,0,1><<<dim3(1, Sa/64), 256, 0, stream>>>(
        buf, 576, r0, wt_proj, nullptr, nullptr, proj_b, x, out, 192, rowmap);
  }

  // ---- MLP branch: out -> out (= x2 + mlp(ln2(x2))) ----
  for (int s = 0; s < nM; ++s){
    long r0 = (long)s*Sm;
    gemm_kernel<192,2,2><<<dim3(4, Sm/64), 256, 0, stream>>>(
        out, 192, r0, wt_m1, ln2_g, ln2_b, b1, nullptr, buf, 768, rowmap);
    gemm_kernel<768,0,3><<<dim3(1, Sm/64), 256, 0, stream>>>(
        buf, 768, r0, wt_m2, nullptr, nullptr, b2, out, out, 192, rowmap);
  }
}

// Round 2
// 1255.407 us; speedup vs baseline: 1.8453x; 1.8453x over previous
//
#include <hip/hip_runtime.h>
#include <math.h>

typedef __attribute__((ext_vector_type(8))) short short8;
typedef __attribute__((ext_vector_type(4))) float floatx4;

#define M_TOT 200704            // 64*56*56 token rows
#define SCALE_Q 0.17677669529663687f   // 32^-0.5

__device__ __forceinline__ float u2f(unsigned int u){ return __uint_as_float(u << 16); }
__device__ __forceinline__ unsigned short f2u(float f){
  unsigned int x = __float_as_uint(f);
  x += 0x7fffu + ((x >> 16) & 1u);       // RNE f32->bf16
  return (unsigned short)(x >> 16);
}

// window-layout row m -> spatial row of x (shift+partition gather; same map is the
// reverse+unshift scatter destination: both are +3 cyclic in each axis)
__device__ __forceinline__ int win_to_x(int m){
  int bb = m / 3136; int rem = m - bb*3136;
  int w = rem / 49, n = rem - w*49;
  int wh = w >> 3, ww = w & 7;
  int i = n / 7, j = n - i*7;
  int p = wh*7 + i + 3; if (p >= 56) p -= 56;
  int q = ww*7 + j + 3; if (q >= 56) q -= 56;
  return bb*3136 + p*56 + q;
}

// ---------------- prep: f32 W[K][N] -> bf16 Wt[N][K]  ----------------
__global__ void conv_wt(const float* __restrict__ in, unsigned short* __restrict__ out,
                        int K, int N){
  int t = blockIdx.x*256 + threadIdx.x;
  if (t < K*N){ int k = t / N, n = t - k*N; out[n*K + k] = f2u(in[t]); }
}
// ---------------- prep: row gather/scatter map ----------------
__global__ void rowmap_k(int* __restrict__ map){
  int t = blockIdx.x*256 + threadIdx.x;
  if (t < M_TOT) map[t] = win_to_x(t);
}

// ---------------- MFMA GEMM: block = 64 rows x 192 cols, 4 waves ----------------
// Each wave owns 64 rows x 48 cols = 4x3 fragments -> 12 MFMA per 7 ds_read_b128
// (MFMA-issue bound, not LDS bound). B staged in LDS in K=96 chunks (Ws 192x100
// shorts = 38.4 KB); A staged full-K (LN modes / K=192) or per-chunk (K=768).
// Total LDS 64 KB (K=192) / 51.2 KB (K=768) -> >=2 blocks/CU for overlap.
// LNMODE 0: none (A bf16 scratch, stride astride)
//        1: LN + gather via rowmap (A = x, f32, stride 192)
//        2: LN, linear global rows (A = out, f32, stride 192)
// EPI 0: +bias, scale cols<192 (QKV)    -> bf16 scratch, stride ostride
// EPI 1: +bias, scatter via rowmap + residual res=x (f32) -> d_out f32
// EPI 2: +bias, exact GELU              -> bf16 scratch, stride ostride
// EPI 3: +bias, residual res=out (in-place, f32)          -> d_out f32
template<int KTOT, int LNMODE, int EPI>
__global__ __launch_bounds__(256, 2) void gemm_kernel(
    const void* __restrict__ A, int astride, long row0g,
    const unsigned short* __restrict__ Wt,     // [nW][KTOT] bf16
    const float* __restrict__ lng, const float* __restrict__ lnb,
    const float* __restrict__ bias, const float* __restrict__ res,
    void* __restrict__ outp, int ostride, const int* __restrict__ rowmap){
  constexpr bool AFULL = (LNMODE != 0) || (KTOT == 192);
  constexpr int ASTR  = AFULL ? 200 : 100;    // shorts; both give <=2-way LDS banks
  constexpr int NCH   = KTOT / 96;            // K chunks of 96
  __shared__ __align__(16) unsigned short As[AFULL ? 64*200 : 64*100];
  __shared__ __align__(16) unsigned short Ws[192*100];
  int tid = threadIdx.x;
  // XCD-bijective swizzle (m204): virtual row-major (by,bx) order so the gx
  // col-blocks sharing an A tile run back-to-back on ONE XCD (L2 A-reuse).
  int gx = gridDim.x;
  int nwg = gx * gridDim.y;
  int orig = blockIdx.y * gx + blockIdx.x;     // HW dispatch order (x fastest)
  int qc = nwg >> 3, rc = nwg & 7;
  int xcd = orig & 7, idxk = orig >> 3;
  int wgid = (xcd < rc ? xcd*(qc+1) : rc*(qc+1) + (xcd-rc)*qc) + idxk;
  int bx = wgid % gx, by = wgid / gx;
  int n0 = bx * 192;
  long lrow0 = (long)by * 64;                  // local (slab) row base
  int lane = tid & 63, wv = tid >> 6;
  int quad = lane >> 4, l16 = lane & 15;

  if constexpr (LNMODE != 0){
    // single-pass staging: each thread owns a 48-col row segment; stats
    // accumulate in registers during the load, 2-shuffle reduce over the
    // 4 lanes of the row, normalize+convert+store once (no LDS re-read).
    int rr = tid >> 2, sub = tid & 3;
    long srow = (LNMODE == 1) ? (long)rowmap[row0g + lrow0 + rr] : (row0g + lrow0 + rr);
    const float* rp = (const float*)A + srow*192 + sub*48;
    float va[48];
    float s = 0.f, q2 = 0.f;
    #pragma unroll
    for (int i = 0; i < 12; ++i){
      float4 f = *(const float4*)(rp + i*4);
      va[i*4+0] = f.x; va[i*4+1] = f.y; va[i*4+2] = f.z; va[i*4+3] = f.w;
      s += (f.x + f.y) + (f.z + f.w);
      q2 = fmaf(f.x, f.x, q2); q2 = fmaf(f.y, f.y, q2);
      q2 = fmaf(f.z, f.z, q2); q2 = fmaf(f.w, f.w, q2);
    }
    s  += __shfl_xor(s, 1);  q2 += __shfl_xor(q2, 1);
    s  += __shfl_xor(s, 2);  q2 += __shfl_xor(q2, 2);
    float mean = s*(1.f/192.f);
    float rs = rsqrtf(q2*(1.f/192.f) - mean*mean + 1e-5f);
    float mrs = mean * rs;
    unsigned short* dst = As + rr*200 + sub*48;
    #pragma unroll
    for (int i = 0; i < 12; ++i){
      float4 g4 = *(const float4*)(lng + sub*48 + i*4);
      float4 b4 = *(const float4*)(lnb + sub*48 + i*4);
      ushort4 o;
      o.x = f2u(fmaf(fmaf(va[i*4+0], rs, -mrs), g4.x, b4.x));
      o.y = f2u(fmaf(fmaf(va[i*4+1], rs, -mrs), g4.y, b4.y));
      o.z = f2u(fmaf(fmaf(va[i*4+2], rs, -mrs), g4.z, b4.z));
      o.w = f2u(fmaf(fmaf(va[i*4+3], rs, -mrs), g4.w, b4.w));
      *(ushort4*)(dst + i*4) = o;
    }
    // first in-loop __syncthreads covers this write
  } else if constexpr (AFULL){
    // full-K A stage (K=192, bf16 source): 64 rows x 24 16B-granules
    #pragma unroll
    for (int it = 0; it < 6; ++it){
      int idx = tid + it*256;
      int rr2 = idx / 24, c16 = idx - rr2*24;
      long asrc = (lrow0 + rr2) * (long)astride + c16*8;
      *(uint4*)(As + rr2*200 + c16*8) = *(const uint4*)((const unsigned short*)A + asrc);
    }
  }

  floatx4 acc[12];
  #pragma unroll
  for (int i = 0; i < 12; ++i) acc[i] = (floatx4){0.f,0.f,0.f,0.f};

  for (int c = 0; c < NCH; ++c){
    if (c) __syncthreads();                    // readers done with prev chunk
    if constexpr (!AFULL){
      // per-chunk A stage (K=768 path): 64 rows x 12 granules
      #pragma unroll
      for (int it = 0; it < 3; ++it){
        int idx = tid + it*256;
        int rr2 = idx / 12, g = idx - rr2*12;
        long asrc = (lrow0 + rr2) * (long)astride + c*96 + g*8;
        *(uint4*)(As + rr2*100 + g*8) = *(const uint4*)((const unsigned short*)A + asrc);
      }
    }
    // B chunk: 192 cols x 12 granules (16B each)
    #pragma unroll
    for (int it = 0; it < 9; ++it){
      int idx = tid + it*256;
      int rr2 = idx / 12, g = idx - rr2*12;
      *(uint4*)(Ws + rr2*100 + g*8) =
          *(const uint4*)(Wt + (long)(n0 + rr2)*KTOT + c*96 + g*8);
    }
    __syncthreads();
    int abase = AFULL ? c*96 : 0;
    #pragma unroll
    for (int kk = 0; kk < 3; ++kk){
      int ko = kk*32 + quad*8;
      short8 af[4];
      #pragma unroll
      for (int m = 0; m < 4; ++m)
        af[m] = *(const short8*)(As + (m*16 + l16)*ASTR + abase + ko);
      #pragma unroll
      for (int n = 0; n < 3; ++n){
        short8 bf = *(const short8*)(Ws + (wv*48 + n*16 + l16)*100 + ko);
        #pragma unroll
        for (int m = 0; m < 4; ++m)
          acc[m*3+n] = __builtin_amdgcn_mfma_f32_16x16x32_bf16(af[m], bf, acc[m*3+n], 0, 0, 0);
      }
    }
  }

  // epilogue: D row = quad*4+reg, col = lane&15 (verified gfx950 C/D mapping)
  #pragma unroll
  for (int m = 0; m < 4; ++m){
    #pragma unroll
    for (int r2 = 0; r2 < 4; ++r2){
      long lm = lrow0 + m*16 + quad*4 + r2;
      long drow = 0;
      if (EPI == 1) drow = rowmap[row0g + lm];
      if (EPI == 3) drow = row0g + lm;
      #pragma unroll
      for (int n = 0; n < 3; ++n){
        int col = n0 + wv*48 + n*16 + l16;
        float v = acc[m*3+n][r2] + bias[col];
        if (EPI == 0){
          if (col < 192) v *= SCALE_Q;
          ((unsigned short*)outp)[lm*(long)ostride + col] = f2u(v);
        } else if (EPI == 1){
          v += res[drow*192 + col];
          ((float*)outp)[drow*192 + col] = v;
        } else if (EPI == 2){
          v = 0.5f*v*(1.0f + erff(v*0.70710678118654752f));
          ((unsigned short*)outp)[lm*(long)ostride + col] = f2u(v);
        } else {
          v += res[drow*192 + col];
          ((float*)outp)[drow*192 + col] = v;
        }
      }
    }
  }
}

// ---------------- window attention: one wave per (window, head), in-place on bf16 qkv ----
__global__ __launch_bounds__(64) void attn_kernel(unsigned short* __restrict__ qkv,
    const float* __restrict__ rpb, long win0g){
  __shared__ float Kf[49*32];
  __shared__ float Vf[49*32];
  __shared__ float biasl[169];
  __shared__ int labs[49];
  int bid = blockIdx.x;
  int wb = bid / 6, head = bid - wb*6;   // wb = local window in slab
  int t = threadIdx.x;
  long base = (long)wb * 49 * 576;
  for (int idx = t; idx < 784; idx += 64){   // 49 rows x 16 bf16-pairs
    int j = idx >> 4, k2 = (idx & 15)*2;
    unsigned int ku = *(const unsigned int*)(qkv + base + j*576 + 192 + head*32 + k2);
    Kf[j*32 + k2] = u2f(ku); Kf[j*32 + k2 + 1] = __uint_as_float(ku & 0xffff0000u);
    unsigned int vu = *(const unsigned int*)(qkv + base + j*576 + 384 + head*32 + k2);
    Vf[j*32 + k2] = u2f(vu); Vf[j*32 + k2 + 1] = __uint_as_float(vu & 0xffff0000u);
  }
  for (int idx = t; idx < 169; idx += 64) biasl[idx] = rpb[idx*6 + head];
  if (t < 49){
    int w = (int)((win0g + wb) & 63);     // window index within its image
    int wh = w >> 3, ww = w & 7;
    int i = t / 7, j = t - i*7;
    int p = wh*7 + i, q = ww*7 + j;       // position in shifted frame
    int fp = (p < 49) ? 0 : ((p < 53) ? 1 : 2);
    int fq = (q < 49) ? 0 : ((q < 53) ? 1 : 2);
    labs[t] = fp*3 + fq;
  }
  __syncthreads();
  if (t >= 49) return;
  float qv[32];
  {
    const uint4* qp = (const uint4*)(qkv + base + (long)t*576 + head*32);
    #pragma unroll
    for (int z = 0; z < 4; ++z){
      uint4 u = qp[z];
      qv[z*8+0]=u2f(u.x); qv[z*8+1]=__uint_as_float(u.x & 0xffff0000u);
      qv[z*8+2]=u2f(u.y); qv[z*8+3]=__uint_as_float(u.y & 0xffff0000u);
      qv[z*8+4]=u2f(u.z); qv[z*8+5]=__uint_as_float(u.z & 0xffff0000u);
      qv[z*8+6]=u2f(u.w); qv[z*8+7]=__uint_as_float(u.w & 0xffff0000u);
    }
  }
  int yi = t / 7, xi = t - yi*7;
  int labi = labs[t];
  float s[49];
  #pragma unroll
  for (int yj = 0; yj < 7; ++yj){
    #pragma unroll
    for (int xj = 0; xj < 7; ++xj){
      int j = yj*7 + xj;
      const float* kr = Kf + j*32;
      float a0=0.f,a1=0.f,a2=0.f,a3=0.f;
      #pragma unroll
      for (int k = 0; k < 32; k += 4){
        a0 = fmaf(qv[k],   kr[k],   a0);
        a1 = fmaf(qv[k+1], kr[k+1], a1);
        a2 = fmaf(qv[k+2], kr[k+2], a2);
        a3 = fmaf(qv[k+3], kr[k+3], a3);
      }
      float sv = (a0+a1)+(a2+a3);
      sv += biasl[(yi - yj + 6)*13 + (xi - xj + 6)];
      sv += (labs[j] == labi) ? 0.0f : -100.0f;
      s[j] = sv;
    }
  }
  float mx = s[0];
  #pragma unroll
  for (int j = 1; j < 49; ++j) mx = fmaxf(mx, s[j]);
  float l = 0.f;
  #pragma unroll
  for (int j = 0; j < 49; ++j){ float e = __expf(s[j]-mx); s[j] = e; l += e; }
  float inv = 1.0f / l;
  float o[32];
  #pragma unroll
  for (int k = 0; k < 32; ++k) o[k] = 0.f;
  #pragma unroll
  for (int j = 0; j < 49; ++j){
    float pj = s[j];
    const float* vr = Vf + j*32;
    #pragma unroll
    for (int k = 0; k < 32; ++k) o[k] = fmaf(pj, vr[k], o[k]);
  }
  // write over own q-slice (block-local, race-free)
  unsigned short* op = qkv + base + (long)t*576 + head*32;
  uint4 ov[4];
  unsigned int* ow = (unsigned int*)ov;
  #pragma unroll
  for (int k2 = 0; k2 < 16; ++k2){
    ow[k2] = (unsigned int)f2u(o[2*k2]*inv) | ((unsigned int)f2u(o[2*k2+1]*inv) << 16);
  }
  uint4* o4 = (uint4*)op;
  #pragma unroll
  for (int z = 0; z < 4; ++z) o4[z] = ov[z];
}

extern "C" void kernel_launch(void* const* d_in, const int* in_sizes, int n_in,
                              void* d_out, int out_size, void* d_ws, size_t ws_size,
                              hipStream_t stream){
  const float* x     = (const float*)d_in[0];
  const float* ln1_g = (const float*)d_in[1];
  const float* ln1_b = (const float*)d_in[2];
  const float* qkv_w = (const float*)d_in[3];
  const float* qkv_b = (const float*)d_in[4];
  const float* proj_w= (const float*)d_in[5];
  const float* proj_b= (const float*)d_in[6];
  const float* rpb   = (const float*)d_in[7];
  const float* ln2_g = (const float*)d_in[8];
  const float* ln2_b = (const float*)d_in[9];
  const float* w1    = (const float*)d_in[10];
  const float* b1    = (const float*)d_in[11];
  const float* w2    = (const float*)d_in[12];
  const float* b2    = (const float*)d_in[13];
  float* out = (float*)d_out;

  // ws layout: bf16 transposed weights | rowmap | activation scratch
  unsigned short* wt_qkv  = (unsigned short*)d_ws;        // 576 x 192
  unsigned short* wt_proj = wt_qkv  + 576*192;            // 192 x 192
  unsigned short* wt_m1   = wt_proj + 192*192;            // 768 x 192
  unsigned short* wt_m2   = wt_m1   + 768*192;            // 192 x 768
  int* rowmap = (int*)(wt_m2 + 192*768);                  // M_TOT ints
  unsigned short* buf = (unsigned short*)(rowmap + M_TOT);
  size_t ovh = (size_t)(576*192 + 192*192 + 768*192 + 192*768)*2 + (size_t)M_TOT*4;
  size_t bufb = ws_size > ovh ? ws_size - ovh : 0;

  // --- slab sizing (depends only on constant ws_size -> identical every call) ---
  int da = 64;
  while (da > 1 && (size_t)3136*(size_t)da*1152ULL > bufb) da >>= 1;
  long Sa = 3136L*da;             // attention slab rows (whole images); qkv bytes = Sa*1152
  int nA = 64/da;
  static const long smlist[] = {200704,100352,50176,25088,12544,6272,3136,1792,1024,512,448,256,128,64};
  long Sm = 64;
  for (int i = 0; i < 14; ++i) if ((size_t)smlist[i]*1536ULL <= bufb){ Sm = smlist[i]; break; }
  int nM = (int)(M_TOT / Sm);

  // ---- prep: weights -> bf16 transposed; row gather map ----
  conv_wt<<<(192*576+255)/256, 256, 0, stream>>>(qkv_w, wt_qkv, 192, 576);
  conv_wt<<<(192*192+255)/256, 256, 0, stream>>>(proj_w, wt_proj, 192, 192);
  conv_wt<<<(192*768+255)/256, 256, 0, stream>>>(w1, wt_m1, 192, 768);
  conv_wt<<<(768*192+255)/256, 256, 0, stream>>>(w2, wt_m2, 768, 192);
  rowmap_k<<<(M_TOT+255)/256, 256, 0, stream>>>(rowmap);

  // ---- attention branch: x -> out (= x + attn(ln1(x))) ----
  for (int s = 0; s < nA; ++s){
    long r0 = (long)s*Sa;
    gemm_kernel<192,1,0><<<dim3(3, Sa/64), 256, 0, stream>>>(
        x, 192, r0, wt_qkv, ln1_g, ln1_b, qkv_b, nullptr, buf, 576, rowmap);
    attn_kernel<<<(int)(Sa/49)*6, 64, 0, stream>>>(buf, rpb, r0/49);
    gemm_kernel<192,0,1><<<dim3(1, Sa/64), 256, 0, stream>>>(
        buf, 576, r0, wt_proj, nullptr, nullptr, proj_b, x, out, 192, rowmap);
  }

  // ---- MLP branch: out -> out (= x2 + mlp(ln2(x2))) ----
  for (int s = 0; s < nM; ++s){
    long r0 = (long)s*Sm;
    gemm_kernel<192,2,2><<<dim3(4, Sm/64), 256, 0, stream>>>(
        out, 192, r0, wt_m1, ln2_g, ln2_b, b1, nullptr, buf, 768, rowmap);
    gemm_kernel<768,0,3><<<dim3(1, Sm/64), 256, 0, stream>>>(
        buf, 768, r0, wt_m2, nullptr, nullptr, b2, out, out, 192, rowmap);
  }
}

// Round 4
// 1071.449 us; speedup vs baseline: 2.1622x; 1.1717x over previous
//
#include <hip/hip_runtime.h>
#include <math.h>

typedef __attribute__((ext_vector_type(8))) short short8;
typedef __attribute__((ext_vector_type(4))) float floatx4;

#define M_TOT 200704            // 64*56*56 token rows
#define SCALE_Q 0.17677669529663687f   // 32^-0.5

__device__ __forceinline__ float u2f(unsigned int u){ return __uint_as_float(u << 16); }
__device__ __forceinline__ unsigned short f2u(float f){
  unsigned int x = __float_as_uint(f);
  x += 0x7fffu + ((x >> 16) & 1u);       // RNE f32->bf16
  return (unsigned short)(x >> 16);
}

// window-layout row m -> spatial row of x (shift+partition gather; same map is the
// reverse+unshift scatter destination: both are +3 cyclic in each axis)
__device__ __forceinline__ int win_to_x(int m){
  int bb = m / 3136; int rem = m - bb*3136;
  int w = rem / 49, n = rem - w*49;
  int wh = w >> 3, ww = w & 7;
  int i = n / 7, j = n - i*7;
  int p = wh*7 + i + 3; if (p >= 56) p -= 56;
  int q = ww*7 + j + 3; if (q >= 56) q -= 56;
  return bb*3136 + p*56 + q;
}

// ---------------- prep: f32 W[K][N] -> bf16 Wt[N][K]  ----------------
__global__ void conv_wt(const float* __restrict__ in, unsigned short* __restrict__ out,
                        int K, int N){
  int t = blockIdx.x*256 + threadIdx.x;
  if (t < K*N){ int k = t / N, n = t - k*N; out[n*K + k] = f2u(in[t]); }
}
// ---------------- prep: row gather/scatter map ----------------
__global__ void rowmap_k(int* __restrict__ map){
  int t = blockIdx.x*256 + threadIdx.x;
  if (t < M_TOT) map[t] = win_to_x(t);
}
// ---------------- prep: bias+mask table BM[w][h][i][j] bf16, 64x64 padded ----
// j>=49 (or i>=49) -> -30000 so padded columns softmax to exactly 0.
__global__ void bm_k(const float* __restrict__ rpb, unsigned short* __restrict__ BM){
  int w = blockIdx.x / 6, h = blockIdx.x - (blockIdx.x/6)*6;
  int t = threadIdx.x;
  unsigned short* o = BM + ((size_t)blockIdx.x << 12);
  int wh = w >> 3, ww = w & 7;
  for (int z = 0; z < 16; ++z){
    int idx = t*16 + z;                 // 0..4095
    int i = idx >> 6, j = idx & 63;
    float val = -30000.0f;
    if (i < 49 && j < 49){
      int yi = i/7, xi = i - (i/7)*7, yj = j/7, xj = j - (j/7)*7;
      int pi_ = wh*7 + yi, qi_ = ww*7 + xi;
      int pj_ = wh*7 + yj, qj_ = ww*7 + xj;
      int li = (pi_<49?0:(pi_<53?1:2))*3 + (qi_<49?0:(qi_<53?1:2));
      int lj = (pj_<49?0:(pj_<53?1:2))*3 + (qj_<49?0:(qj_<53?1:2));
      int rel = (yi-yj+6)*13 + (xi-xj+6);
      val = rpb[rel*6 + h] + ((li == lj) ? 0.0f : -100.0f);
    }
    o[idx] = f2u(val);
  }
}

// ---------------- MFMA GEMM: block = 64 rows x 192 cols, 4 waves ----------------
// (unchanged from round 2 — verified)
template<int KTOT, int LNMODE, int EPI>
__global__ __launch_bounds__(256, 2) void gemm_kernel(
    const void* __restrict__ A, int astride, long row0g,
    const unsigned short* __restrict__ Wt,     // [nW][KTOT] bf16
    const float* __restrict__ lng, const float* __restrict__ lnb,
    const float* __restrict__ bias, const float* __restrict__ res,
    void* __restrict__ outp, int ostride, const int* __restrict__ rowmap){
  constexpr bool AFULL = (LNMODE != 0) || (KTOT == 192);
  constexpr int ASTR  = AFULL ? 200 : 100;    // shorts; both give <=2-way LDS banks
  constexpr int NCH   = KTOT / 96;            // K chunks of 96
  __shared__ __align__(16) unsigned short As[AFULL ? 64*200 : 64*100];
  __shared__ __align__(16) unsigned short Ws[192*100];
  int tid = threadIdx.x;
  int gx = gridDim.x;
  int nwg = gx * gridDim.y;
  int orig = blockIdx.y * gx + blockIdx.x;     // HW dispatch order (x fastest)
  int qc = nwg >> 3, rc = nwg & 7;
  int xcd = orig & 7, idxk = orig >> 3;
  int wgid = (xcd < rc ? xcd*(qc+1) : rc*(qc+1) + (xcd-rc)*qc) + idxk;
  int bx = wgid % gx, by = wgid / gx;
  int n0 = bx * 192;
  long lrow0 = (long)by * 64;                  // local (slab) row base
  int lane = tid & 63, wv = tid >> 6;
  int quad = lane >> 4, l16 = lane & 15;

  if constexpr (LNMODE != 0){
    int rr = tid >> 2, sub = tid & 3;
    long srow = (LNMODE == 1) ? (long)rowmap[row0g + lrow0 + rr] : (row0g + lrow0 + rr);
    const float* rp = (const float*)A + srow*192 + sub*48;
    float va[48];
    float s = 0.f, q2 = 0.f;
    #pragma unroll
    for (int i = 0; i < 12; ++i){
      float4 f = *(const float4*)(rp + i*4);
      va[i*4+0] = f.x; va[i*4+1] = f.y; va[i*4+2] = f.z; va[i*4+3] = f.w;
      s += (f.x + f.y) + (f.z + f.w);
      q2 = fmaf(f.x, f.x, q2); q2 = fmaf(f.y, f.y, q2);
      q2 = fmaf(f.z, f.z, q2); q2 = fmaf(f.w, f.w, q2);
    }
    s  += __shfl_xor(s, 1);  q2 += __shfl_xor(q2, 1);
    s  += __shfl_xor(s, 2);  q2 += __shfl_xor(q2, 2);
    float mean = s*(1.f/192.f);
    float rs = rsqrtf(q2*(1.f/192.f) - mean*mean + 1e-5f);
    float mrs = mean * rs;
    unsigned short* dst = As + rr*200 + sub*48;
    #pragma unroll
    for (int i = 0; i < 12; ++i){
      float4 g4 = *(const float4*)(lng + sub*48 + i*4);
      float4 b4 = *(const float4*)(lnb + sub*48 + i*4);
      ushort4 o;
      o.x = f2u(fmaf(fmaf(va[i*4+0], rs, -mrs), g4.x, b4.x));
      o.y = f2u(fmaf(fmaf(va[i*4+1], rs, -mrs), g4.y, b4.y));
      o.z = f2u(fmaf(fmaf(va[i*4+2], rs, -mrs), g4.z, b4.z));
      o.w = f2u(fmaf(fmaf(va[i*4+3], rs, -mrs), g4.w, b4.w));
      *(ushort4*)(dst + i*4) = o;
    }
    // first in-loop __syncthreads covers this write
  } else if constexpr (AFULL){
    #pragma unroll
    for (int it = 0; it < 6; ++it){
      int idx = tid + it*256;
      int rr2 = idx / 24, c16 = idx - rr2*24;
      long asrc = (lrow0 + rr2) * (long)astride + c16*8;
      *(uint4*)(As + rr2*200 + c16*8) = *(const uint4*)((const unsigned short*)A + asrc);
    }
  }

  floatx4 acc[12];
  #pragma unroll
  for (int i = 0; i < 12; ++i) acc[i] = (floatx4){0.f,0.f,0.f,0.f};

  for (int c = 0; c < NCH; ++c){
    if (c) __syncthreads();                    // readers done with prev chunk
    if constexpr (!AFULL){
      #pragma unroll
      for (int it = 0; it < 3; ++it){
        int idx = tid + it*256;
        int rr2 = idx / 12, g = idx - rr2*12;
        long asrc = (lrow0 + rr2) * (long)astride + c*96 + g*8;
        *(uint4*)(As + rr2*100 + g*8) = *(const uint4*)((const unsigned short*)A + asrc);
      }
    }
    #pragma unroll
    for (int it = 0; it < 9; ++it){
      int idx = tid + it*256;
      int rr2 = idx / 12, g = idx - rr2*12;
      *(uint4*)(Ws + rr2*100 + g*8) =
          *(const uint4*)(Wt + (long)(n0 + rr2)*KTOT + c*96 + g*8);
    }
    __syncthreads();
    int abase = AFULL ? c*96 : 0;
    #pragma unroll
    for (int kk = 0; kk < 3; ++kk){
      int ko = kk*32 + quad*8;
      short8 af[4];
      #pragma unroll
      for (int m = 0; m < 4; ++m)
        af[m] = *(const short8*)(As + (m*16 + l16)*ASTR + abase + ko);
      #pragma unroll
      for (int n = 0; n < 3; ++n){
        short8 bf = *(const short8*)(Ws + (wv*48 + n*16 + l16)*100 + ko);
        #pragma unroll
        for (int m = 0; m < 4; ++m)
          acc[m*3+n] = __builtin_amdgcn_mfma_f32_16x16x32_bf16(af[m], bf, acc[m*3+n], 0, 0, 0);
      }
    }
  }

  #pragma unroll
  for (int m = 0; m < 4; ++m){
    #pragma unroll
    for (int r2 = 0; r2 < 4; ++r2){
      long lm = lrow0 + m*16 + quad*4 + r2;
      long drow = 0;
      if (EPI == 1) drow = rowmap[row0g + lm];
      if (EPI == 3) drow = row0g + lm;
      #pragma unroll
      for (int n = 0; n < 3; ++n){
        int col = n0 + wv*48 + n*16 + l16;
        float v = acc[m*3+n][r2] + bias[col];
        if (EPI == 0){
          if (col < 192) v *= SCALE_Q;
          ((unsigned short*)outp)[lm*(long)ostride + col] = f2u(v);
        } else if (EPI == 1){
          v += res[drow*192 + col];
          ((float*)outp)[drow*192 + col] = v;
        } else if (EPI == 2){
          v = 0.5f*v*(1.0f + erff(v*0.70710678118654752f));
          ((unsigned short*)outp)[lm*(long)ostride + col] = f2u(v);
        } else {
          v += res[drow*192 + col];
          ((float*)outp)[drow*192 + col] = v;
        }
      }
    }
  }
}

// ---------------- MFMA window attention: one wave per (window, head) ----------------
// S^T = K·Q^T via 16x mfma_16x16x32 (A=K rows j, B=Q rows i, both natural row-major,
// fragments loaded directly from global, rows clamped to 48). Bias+mask from the
// precomputed BM table. Softmax over j = rows of S^T -> shfl_xor(16/32) reduce;
// 1/sum applied in-register (i = l16 is lane-local). P packed bf16 -> LDS (b64
// writes of 4 consecutive j). O = P·V via 16 mfma with V^T staged in a 16B-granule
// XOR-swizzled LDS tile (padded cols zeroed so P=0 rows contribute exact 0).
__global__ __launch_bounds__(64) void attn_kernel(unsigned short* __restrict__ qkv,
    const unsigned short* __restrict__ BM, long win0g){
  __shared__ __align__(16) unsigned short Vt[32*64];   // V^T [d][j], swizzled
  __shared__ __align__(16) unsigned short Pl[64*72];   // P [i][j], pad 72
  int bid = blockIdx.x;
  int wb = bid / 6, head = bid - wb*6;
  int t = threadIdx.x;
  int q = t >> 4, l16 = t & 15;
  long base = (long)wb * 49 * 576;
  const unsigned short* qkvb = qkv + base;

  // zero Vt cols j=48..63 (j=48 rewritten with real data below; same-wave DS
  // ops complete in issue order, so the later stage write wins)
  #pragma unroll
  for (int z = 0; z < 8; ++z){
    int idx = t + z*64;
    int d = idx >> 4, jz = 48 + (idx & 15);
    Vt[d*64 + ((((jz>>3) ^ (d&7))<<3) | (jz&7))] = 0;
  }
  // stage V^T (transpose on LDS write; reads coalesce via L2 across head-blocks)
  for (int idx = t; idx < 784; idx += 64){
    int j = idx >> 4, d2 = (idx & 15)*2;
    unsigned int u = *(const unsigned int*)(qkvb + (long)j*576 + 384 + head*32 + d2);
    Vt[d2*64 + ((((j>>3) ^ (d2&7))<<3) | (j&7))]       = (unsigned short)(u & 0xffffu);
    Vt[(d2+1)*64 + ((((j>>3) ^ ((d2+1)&7))<<3) | (j&7))] = (unsigned short)(u >> 16);
  }

  // ---- S^T = K·Q^T ----
  short8 kf[4], qf[4];
  #pragma unroll
  for (int jt = 0; jt < 4; ++jt){
    int j = jt*16 + l16; j = j > 48 ? 48 : j;
    kf[jt] = *(const short8*)(qkvb + (long)j*576 + 192 + head*32 + q*8);
  }
  #pragma unroll
  for (int it = 0; it < 4; ++it){
    int i = it*16 + l16; i = i > 48 ? 48 : i;
    qf[it] = *(const short8*)(qkvb + (long)i*576 + head*32 + q*8);
  }
  floatx4 acc[16];
  #pragma unroll
  for (int z = 0; z < 16; ++z) acc[z] = (floatx4){0.f,0.f,0.f,0.f};
  #pragma unroll
  for (int jt = 0; jt < 4; ++jt){
    #pragma unroll
    for (int it = 0; it < 4; ++it)
      acc[jt*4+it] = __builtin_amdgcn_mfma_f32_16x16x32_bf16(kf[jt], qf[it], acc[jt*4+it], 0, 0, 0);
  }

  // ---- bias+mask, softmax over j, scale by 1/sum, pack P to LDS ----
  int w = (int)((win0g + wb) & 63);
  const unsigned short* bmp = BM + ((size_t)(w*6 + head) << 12);
  #pragma unroll
  for (int it = 0; it < 4; ++it){
    float mx = -3.0e38f;
    #pragma unroll
    for (int jt = 0; jt < 4; ++jt){
      ushort4 bm = *(const ushort4*)(bmp + (it*16 + l16)*64 + jt*16 + q*4);
      floatx4 s = acc[jt*4+it];
      s[0] += u2f(bm.x); s[1] += u2f(bm.y); s[2] += u2f(bm.z); s[3] += u2f(bm.w);
      acc[jt*4+it] = s;
      mx = fmaxf(mx, fmaxf(fmaxf(s[0], s[1]), fmaxf(s[2], s[3])));
    }
    mx = fmaxf(mx, __shfl_xor(mx, 16));
    mx = fmaxf(mx, __shfl_xor(mx, 32));
    float sum = 0.f;
    #pragma unroll
    for (int jt = 0; jt < 4; ++jt){
      floatx4 s = acc[jt*4+it];
      s[0] = __expf(s[0]-mx); s[1] = __expf(s[1]-mx);
      s[2] = __expf(s[2]-mx); s[3] = __expf(s[3]-mx);
      acc[jt*4+it] = s;
      sum += (s[0]+s[1]) + (s[2]+s[3]);
    }
    sum += __shfl_xor(sum, 16);
    sum += __shfl_xor(sum, 32);
    float inv = 1.0f / sum;
    #pragma unroll
    for (int jt = 0; jt < 4; ++jt){
      floatx4 s = acc[jt*4+it];
      ushort4 pk;
      pk.x = f2u(s[0]*inv); pk.y = f2u(s[1]*inv);
      pk.z = f2u(s[2]*inv); pk.w = f2u(s[3]*inv);
      *(ushort4*)(Pl + (it*16 + l16)*72 + jt*16 + q*4) = pk;
    }
  }
  __syncthreads();

  // ---- O = P·V ----
  floatx4 oa[8];
  #pragma unroll
  for (int z = 0; z < 8; ++z) oa[z] = (floatx4){0.f,0.f,0.f,0.f};
  #pragma unroll
  for (int ks = 0; ks < 2; ++ks){
    short8 pf[4];
    #pragma unroll
    for (int mt = 0; mt < 4; ++mt)
      pf[mt] = *(const short8*)(Pl + (mt*16 + l16)*72 + ks*32 + q*8);
    #pragma unroll
    for (int nt = 0; nt < 2; ++nt){
      int d = nt*16 + l16;
      short8 vf = *(const short8*)(Vt + d*64 + (((ks*4 + q) ^ (d&7))<<3));
      #pragma unroll
      for (int mt = 0; mt < 4; ++mt)
        oa[mt*2+nt] = __builtin_amdgcn_mfma_f32_16x16x32_bf16(pf[mt], vf, oa[mt*2+nt], 0, 0, 0);
    }
  }
  // write O over own q-slice (block-local, race-free)
  #pragma unroll
  for (int mt = 0; mt < 4; ++mt){
    #pragma unroll
    for (int r = 0; r < 4; ++r){
      int i = mt*16 + q*4 + r;
      if (i < 49){
        unsigned short* op = qkv + base + (long)i*576 + head*32;
        op[l16]      = f2u(oa[mt*2+0][r]);
        op[16 + l16] = f2u(oa[mt*2+1][r]);
      }
    }
  }
}

extern "C" void kernel_launch(void* const* d_in, const int* in_sizes, int n_in,
                              void* d_out, int out_size, void* d_ws, size_t ws_size,
                              hipStream_t stream){
  const float* x     = (const float*)d_in[0];
  const float* ln1_g = (const float*)d_in[1];
  const float* ln1_b = (const float*)d_in[2];
  const float* qkv_w = (const float*)d_in[3];
  const float* qkv_b = (const float*)d_in[4];
  const float* proj_w= (const float*)d_in[5];
  const float* proj_b= (const float*)d_in[6];
  const float* rpb   = (const float*)d_in[7];
  const float* ln2_g = (const float*)d_in[8];
  const float* ln2_b = (const float*)d_in[9];
  const float* w1    = (const float*)d_in[10];
  const float* b1    = (const float*)d_in[11];
  const float* w2    = (const float*)d_in[12];
  const float* b2    = (const float*)d_in[13];
  float* out = (float*)d_out;

  // ws layout: bf16 transposed weights | rowmap | BM table | activation scratch
  unsigned short* wt_qkv  = (unsigned short*)d_ws;        // 576 x 192
  unsigned short* wt_proj = wt_qkv  + 576*192;            // 192 x 192
  unsigned short* wt_m1   = wt_proj + 192*192;            // 768 x 192
  unsigned short* wt_m2   = wt_m1   + 768*192;            // 192 x 768
  int* rowmap = (int*)(wt_m2 + 192*768);                  // M_TOT ints
  unsigned short* bm = (unsigned short*)(rowmap + M_TOT); // 384 x 4096 bf16
  unsigned short* buf = bm + (size_t)384*4096;
  size_t ovh = (size_t)(576*192 + 192*192 + 768*192 + 192*768)*2 + (size_t)M_TOT*4
             + (size_t)384*4096*2;
  size_t bufb = ws_size > ovh ? ws_size - ovh : 0;

  // --- slab sizing (depends only on constant ws_size -> identical every call) ---
  int da = 64;
  while (da > 1 && (size_t)3136*(size_t)da*1152ULL > bufb) da >>= 1;
  long Sa = 3136L*da;             // attention slab rows (whole images); qkv bytes = Sa*1152
  int nA = 64/da;
  static const long smlist[] = {200704,100352,50176,25088,12544,6272,3136,1792,1024,512,448,256,128,64};
  long Sm = 64;
  for (int i = 0; i < 14; ++i) if ((size_t)smlist[i]*1536ULL <= bufb){ Sm = smlist[i]; break; }
  int nM = (int)(M_TOT / Sm);

  // ---- prep: weights -> bf16 transposed; row gather map; bias+mask table ----
  conv_wt<<<(192*576+255)/256, 256, 0, stream>>>(qkv_w, wt_qkv, 192, 576);
  conv_wt<<<(192*192+255)/256, 256, 0, stream>>>(proj_w, wt_proj, 192, 192);
  conv_wt<<<(192*768+255)/256, 256, 0, stream>>>(w1, wt_m1, 192, 768);
  conv_wt<<<(768*192+255)/256, 256, 0, stream>>>(w2, wt_m2, 768, 192);
  rowmap_k<<<(M_TOT+255)/256, 256, 0, stream>>>(rowmap);
  bm_k<<<384, 256, 0, stream>>>(rpb, bm);

  // ---- attention branch: x -> out (= x + attn(ln1(x))) ----
  for (int s = 0; s < nA; ++s){
    long r0 = (long)s*Sa;
    gemm_kernel<192,1,0><<<dim3(3, Sa/64), 256, 0, stream>>>(
        x, 192, r0, wt_qkv, ln1_g, ln1_b, qkv_b, nullptr, buf, 576, rowmap);
    attn_kernel<<<(int)(Sa/49)*6, 64, 0, stream>>>(buf, bm, r0/49);
    gemm_kernel<192,0,1><<<dim3(1, Sa/64), 256, 0, stream>>>(
        buf, 576, r0, wt_proj, nullptr, nullptr, proj_b, x, out, 192, rowmap);
  }

  // ---- MLP branch: out -> out (= x2 + mlp(ln2(x2))) ----
  for (int s = 0; s < nM; ++s){
    long r0 = (long)s*Sm;
    gemm_kernel<192,2,2><<<dim3(4, Sm/64), 256, 0, stream>>>(
        out, 192, r0, wt_m1, ln2_g, ln2_b, b1, nullptr, buf, 768, rowmap);
    gemm_kernel<768,0,3><<<dim3(1, Sm/64), 256, 0, stream>>>(
        buf, 768, r0, wt_m2, nullptr, nullptr, b2, out, out, 192, rowmap);
  }
}

// Round 5
// 969.577 us; speedup vs baseline: 2.3893x; 1.1051x over previous
//
#include <hip/hip_runtime.h>
#include <math.h>

typedef __attribute__((ext_vector_type(8))) short short8;
typedef __attribute__((ext_vector_type(4))) float floatx4;

#define M_TOT 200704            // 64*56*56 token rows
#define SCALE_Q 0.17677669529663687f   // 32^-0.5

__device__ __forceinline__ float u2f(unsigned int u){ return __uint_as_float(u << 16); }
__device__ __forceinline__ unsigned short f2u(float f){
  unsigned int x = __float_as_uint(f);
  x += 0x7fffu + ((x >> 16) & 1u);       // RNE f32->bf16
  return (unsigned short)(x >> 16);
}

// window-layout row m -> spatial row of x (shift+partition gather; same map is the
// reverse+unshift scatter destination: both are +3 cyclic in each axis)
__device__ __forceinline__ int win_to_x(int m){
  int bb = m / 3136; int rem = m - bb*3136;
  int w = rem / 49, n = rem - w*49;
  int wh = w >> 3, ww = w & 7;
  int i = n / 7, j = n - i*7;
  int p = wh*7 + i + 3; if (p >= 56) p -= 56;
  int q = ww*7 + j + 3; if (q >= 56) q -= 56;
  return bb*3136 + p*56 + q;
}

// ---------------- prep: f32 W[K][N] -> bf16 Wt[N][K]  ----------------
__global__ void conv_wt(const float* __restrict__ in, unsigned short* __restrict__ out,
                        int K, int N){
  int t = blockIdx.x*256 + threadIdx.x;
  if (t < K*N){ int k = t / N, n = t - k*N; out[n*K + k] = f2u(in[t]); }
}
// ---------------- prep: row gather/scatter map ----------------
__global__ void rowmap_k(int* __restrict__ map){
  int t = blockIdx.x*256 + threadIdx.x;
  if (t < M_TOT) map[t] = win_to_x(t);
}
// ---------------- prep: bias+mask table BM[w][h][i][j] bf16, 64x64 padded ----
// j>=49 (or i>=49) -> -30000 so padded columns softmax to exactly 0.
__global__ void bm_k(const float* __restrict__ rpb, unsigned short* __restrict__ BM){
  int w = blockIdx.x / 6, h = blockIdx.x - (blockIdx.x/6)*6;
  int t = threadIdx.x;
  unsigned short* o = BM + ((size_t)blockIdx.x << 12);
  int wh = w >> 3, ww = w & 7;
  for (int z = 0; z < 16; ++z){
    int idx = t*16 + z;                 // 0..4095
    int i = idx >> 6, j = idx & 63;
    float val = -30000.0f;
    if (i < 49 && j < 49){
      int yi = i/7, xi = i - (i/7)*7, yj = j/7, xj = j - (j/7)*7;
      int pi_ = wh*7 + yi, qi_ = ww*7 + xi;
      int pj_ = wh*7 + yj, qj_ = ww*7 + xj;
      int li = (pi_<49?0:(pi_<53?1:2))*3 + (qi_<49?0:(qi_<53?1:2));
      int lj = (pj_<49?0:(pj_<53?1:2))*3 + (qj_<49?0:(qj_<53?1:2));
      int rel = (yi-yj+6)*13 + (xi-xj+6);
      val = rpb[rel*6 + h] + ((li == lj) ? 0.0f : -100.0f);
    }
    o[idx] = f2u(val);
  }
}

// ---------------- MFMA GEMM: block = 8 waves, 128 rows x (NCG*192) cols ----------
// Wave-tile 64x48 (4x3 frags, 12 MFMA / 7 ds_read_b128). K staged in chunks of 64
// (Ws 192x72 = 27.6 KB). A staged ONCE per block (full-K when K=192; per-chunk for
// K=768) and reused across NCG col-groups -> LN/gather done once per 128 rows.
// LDS: 78.8 KB (K=192) / 46 KB (K=768) -> 2 blocks/CU = 16 waves/CU.
// LNMODE 0: none (A bf16 scratch, stride astride)
//        1: LN + gather via rowmap (A = x, f32, stride 192)
//        2: LN, linear global rows (A = out, f32, stride 192)
// EPI 0: +bias, scale cols<192 (QKV)    -> bf16 scratch, stride ostride
// EPI 1: +bias, scatter via rowmap + residual res=x (f32) -> d_out f32
// EPI 2: +bias, exact GELU              -> bf16 scratch, stride ostride
// EPI 3: +bias, residual res=out (in-place, f32)          -> d_out f32
template<int KTOT, int NCG, int LNMODE, int EPI>
__global__ __launch_bounds__(512, 4) void gemm_kernel(
    const void* __restrict__ A, int astride, long row0g,
    const unsigned short* __restrict__ Wt,     // [nW][KTOT] bf16
    const float* __restrict__ lng, const float* __restrict__ lnb,
    const float* __restrict__ bias, const float* __restrict__ res,
    void* __restrict__ outp, int ostride, const int* __restrict__ rowmap){
  constexpr bool AFULL = (KTOT == 192);       // NCG>1 only valid with AFULL
  constexpr int ASTR  = AFULL ? 200 : 72;     // shorts; both ~2-way LDS banks (free)
  constexpr int NCH   = KTOT / 64;            // K chunks of 64
  __shared__ __align__(16) unsigned short As[AFULL ? 128*200 : 128*72];
  __shared__ __align__(16) unsigned short Ws[192*72];
  int tid = threadIdx.x;
  // XCD-bijective swizzle (m204): contiguous chunk of virtual (by,bx) per XCD.
  int gx = gridDim.x;
  int nwg = gx * gridDim.y;
  int orig = blockIdx.y * gx + blockIdx.x;     // HW dispatch order (x fastest)
  int qc = nwg >> 3, rc = nwg & 7;
  int xcd = orig & 7, idxk = orig >> 3;
  int wgid = (xcd < rc ? xcd*(qc+1) : rc*(qc+1) + (xcd-rc)*qc) + idxk;
  int bx = wgid % gx, by = wgid / gx;
  long lrow0 = (long)by * 128;                 // local (slab) row base
  int lane = tid & 63, wv = tid >> 6;
  int rw = wv >> 2, cw = wv & 3;               // row-wave (0..1), col-wave (0..3)
  int quad = lane >> 4, l16 = lane & 15;

  if constexpr (LNMODE != 0){
    // single-pass staging: thread owns a 48-col row segment; stats in registers,
    // 2-shuffle reduce over the 4 lanes of the row, normalize+store once.
    int rr = tid >> 2, sub = tid & 3;          // 128 rows x 4 segments
    long srow = (LNMODE == 1) ? (long)rowmap[row0g + lrow0 + rr] : (row0g + lrow0 + rr);
    const float* rp = (const float*)A + srow*192 + sub*48;
    float va[48];
    float s = 0.f, q2 = 0.f;
    #pragma unroll
    for (int i = 0; i < 12; ++i){
      float4 f = *(const float4*)(rp + i*4);
      va[i*4+0] = f.x; va[i*4+1] = f.y; va[i*4+2] = f.z; va[i*4+3] = f.w;
      s += (f.x + f.y) + (f.z + f.w);
      q2 = fmaf(f.x, f.x, q2); q2 = fmaf(f.y, f.y, q2);
      q2 = fmaf(f.z, f.z, q2); q2 = fmaf(f.w, f.w, q2);
    }
    s  += __shfl_xor(s, 1);  q2 += __shfl_xor(q2, 1);
    s  += __shfl_xor(s, 2);  q2 += __shfl_xor(q2, 2);
    float mean = s*(1.f/192.f);
    float rs = rsqrtf(q2*(1.f/192.f) - mean*mean + 1e-5f);
    float mrs = mean * rs;
    unsigned short* dst = As + rr*200 + sub*48;
    #pragma unroll
    for (int i = 0; i < 12; ++i){
      float4 g4 = *(const float4*)(lng + sub*48 + i*4);
      float4 b4 = *(const float4*)(lnb + sub*48 + i*4);
      ushort4 o;
      o.x = f2u(fmaf(fmaf(va[i*4+0], rs, -mrs), g4.x, b4.x));
      o.y = f2u(fmaf(fmaf(va[i*4+1], rs, -mrs), g4.y, b4.y));
      o.z = f2u(fmaf(fmaf(va[i*4+2], rs, -mrs), g4.z, b4.z));
      o.w = f2u(fmaf(fmaf(va[i*4+3], rs, -mrs), g4.w, b4.w));
      *(ushort4*)(dst + i*4) = o;
    }
    // first in-loop __syncthreads (g=0,c=0 path below) covers this write
  } else if constexpr (AFULL){
    // full-K A stage (K=192, bf16 source): 128 rows x 24 16B-granules
    #pragma unroll
    for (int it = 0; it < 6; ++it){
      int idx = tid + it*512;
      int rr2 = idx / 24, c16 = idx - rr2*24;
      long asrc = (lrow0 + rr2) * (long)astride + c16*8;
      *(uint4*)(As + rr2*200 + c16*8) = *(const uint4*)((const unsigned short*)A + asrc);
    }
  }

  #pragma unroll
  for (int g = 0; g < NCG; ++g){
    int n0 = (bx*NCG + g) * 192;
    floatx4 acc[12];
    #pragma unroll
    for (int i = 0; i < 12; ++i) acc[i] = (floatx4){0.f,0.f,0.f,0.f};

    for (int c = 0; c < NCH; ++c){
      if (g || c) __syncthreads();             // readers done with prev chunk
      if constexpr (!AFULL){
        // per-chunk A stage (K=768): 128 rows x 8 granules
        #pragma unroll
        for (int it = 0; it < 2; ++it){
          int idx = tid + it*512;
          int rr2 = idx >> 3, gr = idx & 7;
          long asrc = (lrow0 + rr2) * (long)astride + c*64 + gr*8;
          *(uint4*)(As + rr2*72 + gr*8) = *(const uint4*)((const unsigned short*)A + asrc);
        }
      }
      // B chunk: 192 cols x 8 granules (16B each)
      #pragma unroll
      for (int it = 0; it < 3; ++it){
        int idx = tid + it*512;
        int rr2 = idx >> 3, gr = idx & 7;
        *(uint4*)(Ws + rr2*72 + gr*8) =
            *(const uint4*)(Wt + (long)(n0 + rr2)*KTOT + c*64 + gr*8);
      }
      __syncthreads();
      int abase = AFULL ? c*64 : 0;
      #pragma unroll
      for (int kk = 0; kk < 2; ++kk){
        int ko = kk*32 + quad*8;
        short8 af[4];
        #pragma unroll
        for (int m = 0; m < 4; ++m)
          af[m] = *(const short8*)(As + (rw*64 + m*16 + l16)*ASTR + abase + ko);
        #pragma unroll
        for (int n = 0; n < 3; ++n){
          short8 bf = *(const short8*)(Ws + (cw*48 + n*16 + l16)*72 + ko);
          #pragma unroll
          for (int m = 0; m < 4; ++m)
            acc[m*3+n] = __builtin_amdgcn_mfma_f32_16x16x32_bf16(af[m], bf, acc[m*3+n], 0, 0, 0);
        }
      }
    }

    // epilogue: D row = quad*4+reg, col = lane&15 (verified gfx950 C/D mapping)
    #pragma unroll
    for (int m = 0; m < 4; ++m){
      #pragma unroll
      for (int r2 = 0; r2 < 4; ++r2){
        long lm = lrow0 + rw*64 + m*16 + quad*4 + r2;
        long drow = 0;
        if (EPI == 1) drow = rowmap[row0g + lm];
        if (EPI == 3) drow = row0g + lm;
        #pragma unroll
        for (int n = 0; n < 3; ++n){
          int col = n0 + cw*48 + n*16 + l16;
          float v = acc[m*3+n][r2] + bias[col];
          if (EPI == 0){
            if (col < 192) v *= SCALE_Q;
            ((unsigned short*)outp)[lm*(long)ostride + col] = f2u(v);
          } else if (EPI == 1){
            v += res[drow*192 + col];
            ((float*)outp)[drow*192 + col] = v;
          } else if (EPI == 2){
            v = 0.5f*v*(1.0f + erff(v*0.70710678118654752f));
            ((unsigned short*)outp)[lm*(long)ostride + col] = f2u(v);
          } else {
            v += res[drow*192 + col];
            ((float*)outp)[drow*192 + col] = v;
          }
        }
      }
    }
  }
}

// ---------------- MFMA window attention: one wave per (window, head) ----------------
// (verified in round 4)
__global__ __launch_bounds__(64) void attn_kernel(unsigned short* __restrict__ qkv,
    const unsigned short* __restrict__ BM, long win0g){
  __shared__ __align__(16) unsigned short Vt[32*64];   // V^T [d][j], swizzled
  __shared__ __align__(16) unsigned short Pl[64*72];   // P [i][j], pad 72
  int bid = blockIdx.x;
  int wb = bid / 6, head = bid - wb*6;
  int t = threadIdx.x;
  int q = t >> 4, l16 = t & 15;
  long base = (long)wb * 49 * 576;
  const unsigned short* qkvb = qkv + base;

  // zero Vt cols j=48..63 (j=48 rewritten below; same-wave DS ops ordered)
  #pragma unroll
  for (int z = 0; z < 8; ++z){
    int idx = t + z*64;
    int d = idx >> 4, jz = 48 + (idx & 15);
    Vt[d*64 + ((((jz>>3) ^ (d&7))<<3) | (jz&7))] = 0;
  }
  // stage V^T (transpose on LDS write)
  for (int idx = t; idx < 784; idx += 64){
    int j = idx >> 4, d2 = (idx & 15)*2;
    unsigned int u = *(const unsigned int*)(qkvb + (long)j*576 + 384 + head*32 + d2);
    Vt[d2*64 + ((((j>>3) ^ (d2&7))<<3) | (j&7))]       = (unsigned short)(u & 0xffffu);
    Vt[(d2+1)*64 + ((((j>>3) ^ ((d2+1)&7))<<3) | (j&7))] = (unsigned short)(u >> 16);
  }

  // ---- S^T = K·Q^T ----
  short8 kf[4], qf[4];
  #pragma unroll
  for (int jt = 0; jt < 4; ++jt){
    int j = jt*16 + l16; j = j > 48 ? 48 : j;
    kf[jt] = *(const short8*)(qkvb + (long)j*576 + 192 + head*32 + q*8);
  }
  #pragma unroll
  for (int it = 0; it < 4; ++it){
    int i = it*16 + l16; i = i > 48 ? 48 : i;
    qf[it] = *(const short8*)(qkvb + (long)i*576 + head*32 + q*8);
  }
  floatx4 acc[16];
  #pragma unroll
  for (int z = 0; z < 16; ++z) acc[z] = (floatx4){0.f,0.f,0.f,0.f};
  #pragma unroll
  for (int jt = 0; jt < 4; ++jt){
    #pragma unroll
    for (int it = 0; it < 4; ++it)
      acc[jt*4+it] = __builtin_amdgcn_mfma_f32_16x16x32_bf16(kf[jt], qf[it], acc[jt*4+it], 0, 0, 0);
  }

  // ---- bias+mask, softmax over j, scale by 1/sum, pack P to LDS ----
  int w = (int)((win0g + wb) & 63);
  const unsigned short* bmp = BM + ((size_t)(w*6 + head) << 12);
  #pragma unroll
  for (int it = 0; it < 4; ++it){
    float mx = -3.0e38f;
    #pragma unroll
    for (int jt = 0; jt < 4; ++jt){
      ushort4 bm = *(const ushort4*)(bmp + (it*16 + l16)*64 + jt*16 + q*4);
      floatx4 s = acc[jt*4+it];
      s[0] += u2f(bm.x); s[1] += u2f(bm.y); s[2] += u2f(bm.z); s[3] += u2f(bm.w);
      acc[jt*4+it] = s;
      mx = fmaxf(mx, fmaxf(fmaxf(s[0], s[1]), fmaxf(s[2], s[3])));
    }
    mx = fmaxf(mx, __shfl_xor(mx, 16));
    mx = fmaxf(mx, __shfl_xor(mx, 32));
    float sum = 0.f;
    #pragma unroll
    for (int jt = 0; jt < 4; ++jt){
      floatx4 s = acc[jt*4+it];
      s[0] = __expf(s[0]-mx); s[1] = __expf(s[1]-mx);
      s[2] = __expf(s[2]-mx); s[3] = __expf(s[3]-mx);
      acc[jt*4+it] = s;
      sum += (s[0]+s[1]) + (s[2]+s[3]);
    }
    sum += __shfl_xor(sum, 16);
    sum += __shfl_xor(sum, 32);
    float inv = 1.0f / sum;
    #pragma unroll
    for (int jt = 0; jt < 4; ++jt){
      floatx4 s = acc[jt*4+it];
      ushort4 pk;
      pk.x = f2u(s[0]*inv); pk.y = f2u(s[1]*inv);
      pk.z = f2u(s[2]*inv); pk.w = f2u(s[3]*inv);
      *(ushort4*)(Pl + (it*16 + l16)*72 + jt*16 + q*4) = pk;
    }
  }
  __syncthreads();

  // ---- O = P·V ----
  floatx4 oa[8];
  #pragma unroll
  for (int z = 0; z < 8; ++z) oa[z] = (floatx4){0.f,0.f,0.f,0.f};
  #pragma unroll
  for (int ks = 0; ks < 2; ++ks){
    short8 pf[4];
    #pragma unroll
    for (int mt = 0; mt < 4; ++mt)
      pf[mt] = *(const short8*)(Pl + (mt*16 + l16)*72 + ks*32 + q*8);
    #pragma unroll
    for (int nt = 0; nt < 2; ++nt){
      int d = nt*16 + l16;
      short8 vf = *(const short8*)(Vt + d*64 + (((ks*4 + q) ^ (d&7))<<3));
      #pragma unroll
      for (int mt = 0; mt < 4; ++mt)
        oa[mt*2+nt] = __builtin_amdgcn_mfma_f32_16x16x32_bf16(pf[mt], vf, oa[mt*2+nt], 0, 0, 0);
    }
  }
  // write O over own q-slice (block-local, race-free)
  #pragma unroll
  for (int mt = 0; mt < 4; ++mt){
    #pragma unroll
    for (int r = 0; r < 4; ++r){
      int i = mt*16 + q*4 + r;
      if (i < 49){
        unsigned short* op = qkv + base + (long)i*576 + head*32;
        op[l16]      = f2u(oa[mt*2+0][r]);
        op[16 + l16] = f2u(oa[mt*2+1][r]);
      }
    }
  }
}

extern "C" void kernel_launch(void* const* d_in, const int* in_sizes, int n_in,
                              void* d_out, int out_size, void* d_ws, size_t ws_size,
                              hipStream_t stream){
  const float* x     = (const float*)d_in[0];
  const float* ln1_g = (const float*)d_in[1];
  const float* ln1_b = (const float*)d_in[2];
  const float* qkv_w = (const float*)d_in[3];
  const float* qkv_b = (const float*)d_in[4];
  const float* proj_w= (const float*)d_in[5];
  const float* proj_b= (const float*)d_in[6];
  const float* rpb   = (const float*)d_in[7];
  const float* ln2_g = (const float*)d_in[8];
  const float* ln2_b = (const float*)d_in[9];
  const float* w1    = (const float*)d_in[10];
  const float* b1    = (const float*)d_in[11];
  const float* w2    = (const float*)d_in[12];
  const float* b2    = (const float*)d_in[13];
  float* out = (float*)d_out;

  // ws layout: bf16 transposed weights | rowmap | BM table | activation scratch
  unsigned short* wt_qkv  = (unsigned short*)d_ws;        // 576 x 192
  unsigned short* wt_proj = wt_qkv  + 576*192;            // 192 x 192
  unsigned short* wt_m1   = wt_proj + 192*192;            // 768 x 192
  unsigned short* wt_m2   = wt_m1   + 768*192;            // 192 x 768
  int* rowmap = (int*)(wt_m2 + 192*768);                  // M_TOT ints
  unsigned short* bm = (unsigned short*)(rowmap + M_TOT); // 384 x 4096 bf16
  unsigned short* buf = bm + (size_t)384*4096;
  size_t ovh = (size_t)(576*192 + 192*192 + 768*192 + 192*768)*2 + (size_t)M_TOT*4
             + (size_t)384*4096*2;
  size_t bufb = ws_size > ovh ? ws_size - ovh : 0;

  // --- slab sizing: multiples of 128 rows (gy = rows/128) ---
  int da = 64;
  while (da > 2 && (size_t)3136*(size_t)da*1152ULL > bufb) da >>= 1;
  long Sa = 3136L*da;             // attention slab rows (whole images, da even)
  int nA = 64/da;
  static const long smlist[] = {200704,100352,50176,25088,12544,6272,1792,1024,512,256,128};
  long Sm = 128;
  for (int i = 0; i < 11; ++i) if ((size_t)smlist[i]*1536ULL <= bufb){ Sm = smlist[i]; break; }
  int nM = (int)(M_TOT / Sm);

  // ---- prep: weights -> bf16 transposed; row gather map; bias+mask table ----
  conv_wt<<<(192*576+255)/256, 256, 0, stream>>>(qkv_w, wt_qkv, 192, 576);
  conv_wt<<<(192*192+255)/256, 256, 0, stream>>>(proj_w, wt_proj, 192, 192);
  conv_wt<<<(192*768+255)/256, 256, 0, stream>>>(w1, wt_m1, 192, 768);
  conv_wt<<<(768*192+255)/256, 256, 0, stream>>>(w2, wt_m2, 768, 192);
  rowmap_k<<<(M_TOT+255)/256, 256, 0, stream>>>(rowmap);
  bm_k<<<384, 256, 0, stream>>>(rpb, bm);

  // ---- attention branch: x -> out (= x + attn(ln1(x))) ----
  for (int s = 0; s < nA; ++s){
    long r0 = (long)s*Sa;
    gemm_kernel<192,3,1,0><<<dim3(1, Sa/128), 512, 0, stream>>>(
        x, 192, r0, wt_qkv, ln1_g, ln1_b, qkv_b, nullptr, buf, 576, rowmap);
    attn_kernel<<<(int)(Sa/49)*6, 64, 0, stream>>>(buf, bm, r0/49);
    gemm_kernel<192,1,0,1><<<dim3(1, Sa/128), 512, 0, stream>>>(
        buf, 576, r0, wt_proj, nullptr, nullptr, proj_b, x, out, 192, rowmap);
  }

  // ---- MLP branch: out -> out (= x2 + mlp(ln2(x2))) ----
  for (int s = 0; s < nM; ++s){
    long r0 = (long)s*Sm;
    gemm_kernel<192,2,2,2><<<dim3(2, Sm/128), 512, 0, stream>>>(
        out, 192, r0, wt_m1, ln2_g, ln2_b, b1, nullptr, buf, 768, rowmap);
    gemm_kernel<768,1,0,3><<<dim3(1, Sm/128), 512, 0, stream>>>(
        buf, 768, r0, wt_m2, nullptr, nullptr, b2, out, out, 192, rowmap);
  }
}

// Round 6
// 931.232 us; speedup vs baseline: 2.4877x; 1.0412x over previous
//
#include <hip/hip_runtime.h>
#include <math.h>

typedef __attribute__((ext_vector_type(8))) short short8;
typedef __attribute__((ext_vector_type(4))) float floatx4;

#define M_TOT 200704            // 64*56*56 token rows
#define SCALE_Q 0.17677669529663687f   // 32^-0.5

__device__ __forceinline__ float u2f(unsigned int u){ return __uint_as_float(u << 16); }
__device__ __forceinline__ unsigned short f2u(float f){
  unsigned int x = __float_as_uint(f);
  x += 0x7fffu + ((x >> 16) & 1u);       // RNE f32->bf16
  return (unsigned short)(x >> 16);
}

// async global->LDS, 16B per lane; LDS dest is wave-uniform base + lane*16
#define GLD16(gp, lp) __builtin_amdgcn_global_load_lds( \
    (const __attribute__((address_space(1))) void*)(gp), \
    (__attribute__((address_space(3))) void*)(lp), 16, 0, 0)

// window-layout row m -> spatial row of x (shift+partition gather; same map is the
// reverse+unshift scatter destination: both are +3 cyclic in each axis)
__device__ __forceinline__ int win_to_x(int m){
  int bb = m / 3136; int rem = m - bb*3136;
  int w = rem / 49, n = rem - w*49;
  int wh = w >> 3, ww = w & 7;
  int i = n / 7, j = n - i*7;
  int p = wh*7 + i + 3; if (p >= 56) p -= 56;
  int q = ww*7 + j + 3; if (q >= 56) q -= 56;
  return bb*3136 + p*56 + q;
}

// ---------------- prep: f32 W[K][N] -> bf16 Wt[N][K] ----------------
// indexed by OUTPUT element: coalesced writes, scattered reads (L2-absorbed)
__global__ void conv_wt(const float* __restrict__ in, unsigned short* __restrict__ out,
                        int K, int N){
  int t = blockIdx.x*256 + threadIdx.x;
  if (t < K*N){ int n = t / K, k = t - n*K; out[t] = f2u(in[k*N + n]); }
}
// ---------------- prep: row gather/scatter map ----------------
__global__ void rowmap_k(int* __restrict__ map){
  int t = blockIdx.x*256 + threadIdx.x;
  if (t < M_TOT) map[t] = win_to_x(t);
}
// ---------------- prep: bias+mask table BM[w][h][i][j] bf16, 64x64 padded ----
// j>=49 (or i>=49) -> -30000 so padded columns softmax to exactly 0.
__global__ void bm_k(const float* __restrict__ rpb, unsigned short* __restrict__ BM){
  int w = blockIdx.x / 6, h = blockIdx.x - (blockIdx.x/6)*6;
  int t = threadIdx.x;
  unsigned short* o = BM + ((size_t)blockIdx.x << 12);
  int wh = w >> 3, ww = w & 7;
  for (int z = 0; z < 16; ++z){
    int idx = t*16 + z;                 // 0..4095
    int i = idx >> 6, j = idx & 63;
    float val = -30000.0f;
    if (i < 49 && j < 49){
      int yi = i/7, xi = i - (i/7)*7, yj = j/7, xj = j - (j/7)*7;
      int pi_ = wh*7 + yi, qi_ = ww*7 + xi;
      int pj_ = wh*7 + yj, qj_ = ww*7 + xj;
      int li = (pi_<49?0:(pi_<53?1:2))*3 + (qi_<49?0:(qi_<53?1:2));
      int lj = (pj_<49?0:(pj_<53?1:2))*3 + (qj_<49?0:(qj_<53?1:2));
      int rel = (yi-yj+6)*13 + (xi-xj+6);
      val = rpb[rel*6 + h] + ((li == lj) ? 0.0f : -100.0f);
    }
    o[idx] = f2u(val);
  }
}

// ---------------- MFMA GEMM: block = 8 waves, 128 rows x (NCG*192) cols ----------
// Staging via global_load_lds (16B/lane, linear LDS dest) with granule XOR-swizzle
// (slot = g ^ (row&7)) applied on the SOURCE address and on every ds_read -> padless
// rows (A 384B, W 128B) with <=2-way bank aliasing. Wave-tile 64x48 (4x3 frags).
// K chunks of 64. A staged once per block (full-K when K=192) and reused across NCG
// col-groups. LDS: 73.7 KB (K=192, 2 blk/CU) / 41 KB (K=768, 3 blk/CU).
// LNMODE 0: none (A bf16, stride astride)    1: LN + gather (A=x f32)
//        2: LN, linear rows (A=out f32)
// EPI 0: +bias, scale cols<192 (QKV) -> bf16   1: +bias, scatter + res=x -> f32
//     2: +bias, fast GELU -> bf16               3: +bias, res=out -> f32
template<int KTOT, int NCG, int LNMODE, int EPI>
__global__ __launch_bounds__(512, 4) void gemm_kernel(
    const void* __restrict__ A, int astride, long row0g,
    const unsigned short* __restrict__ Wt,     // [nW][KTOT] bf16
    const float* __restrict__ lng, const float* __restrict__ lnb,
    const float* __restrict__ bias, const float* __restrict__ res,
    void* __restrict__ outp, int ostride, const int* __restrict__ rowmap){
  constexpr bool AFULL = (KTOT == 192);       // NCG>1 only valid with AFULL
  constexpr int AROW  = AFULL ? 192 : 64;     // shorts per As row (padless)
  constexpr int NCH   = KTOT / 64;            // K chunks of 64
  __shared__ __align__(16) unsigned short As[AFULL ? 128*192 : 128*64];
  __shared__ __align__(16) unsigned short Ws[192*64];
  int tid = threadIdx.x;
  // XCD-bijective swizzle (m204): contiguous chunk of virtual (by,bx) per XCD.
  int gx = gridDim.x;
  int nwg = gx * gridDim.y;
  int orig = blockIdx.y * gx + blockIdx.x;     // HW dispatch order (x fastest)
  int qc = nwg >> 3, rc = nwg & 7;
  int xcd = orig & 7, idxk = orig >> 3;
  int wgid = (xcd < rc ? xcd*(qc+1) : rc*(qc+1) + (xcd-rc)*qc) + idxk;
  int bx = wgid % gx, by = wgid / gx;
  long lrow0 = (long)by * 128;                 // local (slab) row base
  int lane = tid & 63, wv = tid >> 6;
  int rw = wv >> 2, cw = wv & 3;               // row-wave (0..1), col-wave (0..3)
  int quad = lane >> 4, l16 = lane & 15;

  if constexpr (LNMODE != 0){
    // single-pass staging: thread owns a 48-col row segment; stats in registers,
    // 2-shuffle reduce over the 4 lanes of the row, normalize+store once into the
    // swizzled As layout (granule slot = g ^ (row&7)).
    int rr = tid >> 2, sub = tid & 3;          // 128 rows x 4 segments
    long srow = (LNMODE == 1) ? (long)rowmap[row0g + lrow0 + rr] : (row0g + lrow0 + rr);
    const float* rp = (const float*)A + srow*192 + sub*48;
    float va[48];
    float s = 0.f, q2 = 0.f;
    #pragma unroll
    for (int i = 0; i < 12; ++i){
      float4 f = *(const float4*)(rp + i*4);
      va[i*4+0] = f.x; va[i*4+1] = f.y; va[i*4+2] = f.z; va[i*4+3] = f.w;
      s += (f.x + f.y) + (f.z + f.w);
      q2 = fmaf(f.x, f.x, q2); q2 = fmaf(f.y, f.y, q2);
      q2 = fmaf(f.z, f.z, q2); q2 = fmaf(f.w, f.w, q2);
    }
    s  += __shfl_xor(s, 1);  q2 += __shfl_xor(q2, 1);
    s  += __shfl_xor(s, 2);  q2 += __shfl_xor(q2, 2);
    float mean = s*(1.f/192.f);
    float rs = rsqrtf(q2*(1.f/192.f) - mean*mean + 1e-5f);
    float mrs = mean * rs;
    unsigned short* dstb = As + rr*192;
    #pragma unroll
    for (int i = 0; i < 12; ++i){
      float4 g4 = *(const float4*)(lng + sub*48 + i*4);
      float4 b4 = *(const float4*)(lnb + sub*48 + i*4);
      ushort4 o;
      o.x = f2u(fmaf(fmaf(va[i*4+0], rs, -mrs), g4.x, b4.x));
      o.y = f2u(fmaf(fmaf(va[i*4+1], rs, -mrs), g4.y, b4.y));
      o.z = f2u(fmaf(fmaf(va[i*4+2], rs, -mrs), g4.z, b4.z));
      o.w = f2u(fmaf(fmaf(va[i*4+3], rs, -mrs), g4.w, b4.w));
      *(ushort4*)(dstb + (((sub*6 + (i>>1)) ^ (rr&7))<<3) + ((i&1)<<2)) = o;
    }
    // first in-loop __syncthreads (g=0,c=0 path below) covers this write
  } else if constexpr (AFULL){
    // full-K A stage via global_load_lds: 48 wave-issues of 1024B, 6 per wave.
    // linear LDS granule gi = r*24+g holds source granule (g ^ (r&7)).
    #pragma unroll
    for (int it = 0; it < 6; ++it){
      int gi = (wv*6 + it)*64 + lane;
      int r = gi / 24, g = gi - r*24;
      const unsigned short* src = (const unsigned short*)A
          + (lrow0 + r)*(long)astride + ((g ^ (r&7))<<3);
      GLD16(src, As + ((wv*6 + it)<<9));
    }
  }

  #pragma unroll
  for (int g = 0; g < NCG; ++g){
    int n0 = (bx*NCG + g) * 192;
    floatx4 acc[12];
    #pragma unroll
    for (int i = 0; i < 12; ++i) acc[i] = (floatx4){0.f,0.f,0.f,0.f};

    for (int c = 0; c < NCH; ++c){
      if (g || c) __syncthreads();             // readers done with prev chunk
      if constexpr (!AFULL){
        // per-chunk A stage (K=768): 16 wave-issues, 2 per wave
        #pragma unroll
        for (int it = 0; it < 2; ++it){
          int gi = (wv*2 + it)*64 + lane;
          int r = gi >> 3, gg = gi & 7;
          const unsigned short* src = (const unsigned short*)A
              + (lrow0 + r)*(long)astride + c*64 + ((gg ^ (r&7))<<3);
          GLD16(src, As + ((wv*2 + it)<<9));
        }
      }
      // B chunk: 192 rows x 8 granules = 24 wave-issues, 3 per wave
      #pragma unroll
      for (int it = 0; it < 3; ++it){
        int gi = (wv*3 + it)*64 + lane;
        int r = gi >> 3, gg = gi & 7;
        const unsigned short* src = Wt + (long)(n0 + r)*KTOT + c*64 + ((gg ^ (r&7))<<3);
        GLD16(src, Ws + ((wv*3 + it)<<9));
      }
      __syncthreads();                         // drains vmcnt (gload_lds) + lgkm
      int gA0 = AFULL ? c*8 : 0;
      #pragma unroll
      for (int kk = 0; kk < 2; ++kk){
        int ga = gA0 + kk*4 + quad;
        short8 af[4];
        #pragma unroll
        for (int m = 0; m < 4; ++m){
          int r = rw*64 + m*16 + l16;
          af[m] = *(const short8*)(As + r*AROW + ((ga ^ (r&7))<<3));
        }
        int gb = kk*4 + quad;
        #pragma unroll
        for (int n = 0; n < 3; ++n){
          int rb = cw*48 + n*16 + l16;
          short8 bf = *(const short8*)(Ws + rb*64 + ((gb ^ (rb&7))<<3));
          #pragma unroll
          for (int m = 0; m < 4; ++m)
            acc[m*3+n] = __builtin_amdgcn_mfma_f32_16x16x32_bf16(af[m], bf, acc[m*3+n], 0, 0, 0);
        }
      }
    }

    // epilogue: D row = quad*4+reg, col = lane&15 (verified gfx950 C/D mapping)
    #pragma unroll
    for (int m = 0; m < 4; ++m){
      #pragma unroll
      for (int r2 = 0; r2 < 4; ++r2){
        long lm = lrow0 + rw*64 + m*16 + quad*4 + r2;
        long drow = 0;
        if (EPI == 1) drow = rowmap[row0g + lm];
        if (EPI == 3) drow = row0g + lm;
        #pragma unroll
        for (int n = 0; n < 3; ++n){
          int col = n0 + cw*48 + n*16 + l16;
          float v = acc[m*3+n][r2] + bias[col];
          if (EPI == 0){
            if (col < 192) v *= SCALE_Q;
            ((unsigned short*)outp)[lm*(long)ostride + col] = f2u(v);
          } else if (EPI == 1){
            v += res[drow*192 + col];
            ((float*)outp)[drow*192 + col] = v;
          } else if (EPI == 2){
            // tanh-form GELU: v * sigmoid(1.59577*v*(1+0.044715*v^2));
            // max |err| vs exact erf-GELU ~3e-4, invisible under bf16 rounding
            float zz = 1.5957691216057308f * v * fmaf(v*v, 0.044715f, 1.0f);
            v = v * __builtin_amdgcn_rcpf(1.0f + __expf(-zz));
            ((unsigned short*)outp)[lm*(long)ostride + col] = f2u(v);
          } else {
            v += res[drow*192 + col];
            ((float*)outp)[drow*192 + col] = v;
          }
        }
      }
    }
  }
}

// ---------------- MFMA window attention: one wave per (window, head) ----------------
// (verified in round 4)
__global__ __launch_bounds__(64) void attn_kernel(unsigned short* __restrict__ qkv,
    const unsigned short* __restrict__ BM, long win0g){
  __shared__ __align__(16) unsigned short Vt[32*64];   // V^T [d][j], swizzled
  __shared__ __align__(16) unsigned short Pl[64*72];   // P [i][j], pad 72
  int bid = blockIdx.x;
  int wb = bid / 6, head = bid - wb*6;
  int t = threadIdx.x;
  int q = t >> 4, l16 = t & 15;
  long base = (long)wb * 49 * 576;
  const unsigned short* qkvb = qkv + base;

  // zero Vt cols j=48..63 (j=48 rewritten below; same-wave DS ops ordered)
  #pragma unroll
  for (int z = 0; z < 8; ++z){
    int idx = t + z*64;
    int d = idx >> 4, jz = 48 + (idx & 15);
    Vt[d*64 + ((((jz>>3) ^ (d&7))<<3) | (jz&7))] = 0;
  }
  // stage V^T (transpose on LDS write)
  for (int idx = t; idx < 784; idx += 64){
    int j = idx >> 4, d2 = (idx & 15)*2;
    unsigned int u = *(const unsigned int*)(qkvb + (long)j*576 + 384 + head*32 + d2);
    Vt[d2*64 + ((((j>>3) ^ (d2&7))<<3) | (j&7))]       = (unsigned short)(u & 0xffffu);
    Vt[(d2+1)*64 + ((((j>>3) ^ ((d2+1)&7))<<3) | (j&7))] = (unsigned short)(u >> 16);
  }

  // ---- S^T = K·Q^T ----
  short8 kf[4], qf[4];
  #pragma unroll
  for (int jt = 0; jt < 4; ++jt){
    int j = jt*16 + l16; j = j > 48 ? 48 : j;
    kf[jt] = *(const short8*)(qkvb + (long)j*576 + 192 + head*32 + q*8);
  }
  #pragma unroll
  for (int it = 0; it < 4; ++it){
    int i = it*16 + l16; i = i > 48 ? 48 : i;
    qf[it] = *(const short8*)(qkvb + (long)i*576 + head*32 + q*8);
  }
  floatx4 acc[16];
  #pragma unroll
  for (int z = 0; z < 16; ++z) acc[z] = (floatx4){0.f,0.f,0.f,0.f};
  #pragma unroll
  for (int jt = 0; jt < 4; ++jt){
    #pragma unroll
    for (int it = 0; it < 4; ++it)
      acc[jt*4+it] = __builtin_amdgcn_mfma_f32_16x16x32_bf16(kf[jt], qf[it], acc[jt*4+it], 0, 0, 0);
  }

  // ---- bias+mask, softmax over j, scale by 1/sum, pack P to LDS ----
  int w = (int)((win0g + wb) & 63);
  const unsigned short* bmp = BM + ((size_t)(w*6 + head) << 12);
  #pragma unroll
  for (int it = 0; it < 4; ++it){
    float mx = -3.0e38f;
    #pragma unroll
    for (int jt = 0; jt < 4; ++jt){
      ushort4 bm = *(const ushort4*)(bmp + (it*16 + l16)*64 + jt*16 + q*4);
      floatx4 s = acc[jt*4+it];
      s[0] += u2f(bm.x); s[1] += u2f(bm.y); s[2] += u2f(bm.z); s[3] += u2f(bm.w);
      acc[jt*4+it] = s;
      mx = fmaxf(mx, fmaxf(fmaxf(s[0], s[1]), fmaxf(s[2], s[3])));
    }
    mx = fmaxf(mx, __shfl_xor(mx, 16));
    mx = fmaxf(mx, __shfl_xor(mx, 32));
    float sum = 0.f;
    #pragma unroll
    for (int jt = 0; jt < 4; ++jt){
      floatx4 s = acc[jt*4+it];
      s[0] = __expf(s[0]-mx); s[1] = __expf(s[1]-mx);
      s[2] = __expf(s[2]-mx); s[3] = __expf(s[3]-mx);
      acc[jt*4+it] = s;
      sum += (s[0]+s[1]) + (s[2]+s[3]);
    }
    sum += __shfl_xor(sum, 16);
    sum += __shfl_xor(sum, 32);
    float inv = 1.0f / sum;
    #pragma unroll
    for (int jt = 0; jt < 4; ++jt){
      floatx4 s = acc[jt*4+it];
      ushort4 pk;
      pk.x = f2u(s[0]*inv); pk.y = f2u(s[1]*inv);
      pk.z = f2u(s[2]*inv); pk.w = f2u(s[3]*inv);
      *(ushort4*)(Pl + (it*16 + l16)*72 + jt*16 + q*4) = pk;
    }
  }
  __syncthreads();

  // ---- O = P·V ----
  floatx4 oa[8];
  #pragma unroll
  for (int z = 0; z < 8; ++z) oa[z] = (floatx4){0.f,0.f,0.f,0.f};
  #pragma unroll
  for (int ks = 0; ks < 2; ++ks){
    short8 pf[4];
    #pragma unroll
    for (int mt = 0; mt < 4; ++mt)
      pf[mt] = *(const short8*)(Pl + (mt*16 + l16)*72 + ks*32 + q*8);
    #pragma unroll
    for (int nt = 0; nt < 2; ++nt){
      int d = nt*16 + l16;
      short8 vf = *(const short8*)(Vt + d*64 + (((ks*4 + q) ^ (d&7))<<3));
      #pragma unroll
      for (int mt = 0; mt < 4; ++mt)
        oa[mt*2+nt] = __builtin_amdgcn_mfma_f32_16x16x32_bf16(pf[mt], vf, oa[mt*2+nt], 0, 0, 0);
    }
  }
  // write O over own q-slice (block-local, race-free)
  #pragma unroll
  for (int mt = 0; mt < 4; ++mt){
    #pragma unroll
    for (int r = 0; r < 4; ++r){
      int i = mt*16 + q*4 + r;
      if (i < 49){
        unsigned short* op = qkv + base + (long)i*576 + head*32;
        op[l16]      = f2u(oa[mt*2+0][r]);
        op[16 + l16] = f2u(oa[mt*2+1][r]);
      }
    }
  }
}

extern "C" void kernel_launch(void* const* d_in, const int* in_sizes, int n_in,
                              void* d_out, int out_size, void* d_ws, size_t ws_size,
                              hipStream_t stream){
  const float* x     = (const float*)d_in[0];
  const float* ln1_g = (const float*)d_in[1];
  const float* ln1_b = (const float*)d_in[2];
  const float* qkv_w = (const float*)d_in[3];
  const float* qkv_b = (const float*)d_in[4];
  const float* proj_w= (const float*)d_in[5];
  const float* proj_b= (const float*)d_in[6];
  const float* rpb   = (const float*)d_in[7];
  const float* ln2_g = (const float*)d_in[8];
  const float* ln2_b = (const float*)d_in[9];
  const float* w1    = (const float*)d_in[10];
  const float* b1    = (const float*)d_in[11];
  const float* w2    = (const float*)d_in[12];
  const float* b2    = (const float*)d_in[13];
  float* out = (float*)d_out;

  // ws layout: bf16 transposed weights | rowmap | BM table | activation scratch
  unsigned short* wt_qkv  = (unsigned short*)d_ws;        // 576 x 192
  unsigned short* wt_proj = wt_qkv  + 576*192;            // 192 x 192
  unsigned short* wt_m1   = wt_proj + 192*192;            // 768 x 192
  unsigned short* wt_m2   = wt_m1   + 768*192;            // 192 x 768
  int* rowmap = (int*)(wt_m2 + 192*768);                  // M_TOT ints
  unsigned short* bm = (unsigned short*)(rowmap + M_TOT); // 384 x 4096 bf16
  unsigned short* buf = bm + (size_t)384*4096;
  size_t ovh = (size_t)(576*192 + 192*192 + 768*192 + 192*768)*2 + (size_t)M_TOT*4
             + (size_t)384*4096*2;
  size_t bufb = ws_size > ovh ? ws_size - ovh : 0;

  // --- slab sizing: multiples of 128 rows (gy = rows/128) ---
  int da = 64;
  while (da > 2 && (size_t)3136*(size_t)da*1152ULL > bufb) da >>= 1;
  long Sa = 3136L*da;             // attention slab rows (whole images, da even)
  int nA = 64/da;
  static const long smlist[] = {200704,100352,50176,25088,12544,6272,1792,1024,512,256,128};
  long Sm = 128;
  for (int i = 0; i < 11; ++i) if ((size_t)smlist[i]*1536ULL <= bufb){ Sm = smlist[i]; break; }
  int nM = (int)(M_TOT / Sm);

  // ---- prep: weights -> bf16 transposed; row gather map; bias+mask table ----
  conv_wt<<<(192*576+255)/256, 256, 0, stream>>>(qkv_w, wt_qkv, 192, 576);
  conv_wt<<<(192*192+255)/256, 256, 0, stream>>>(proj_w, wt_proj, 192, 192);
  conv_wt<<<(192*768+255)/256, 256, 0, stream>>>(w1, wt_m1, 192, 768);
  conv_wt<<<(768*192+255)/256, 256, 0, stream>>>(w2, wt_m2, 768, 192);
  rowmap_k<<<(M_TOT+255)/256, 256, 0, stream>>>(rowmap);
  bm_k<<<384, 256, 0, stream>>>(rpb, bm);

  // ---- attention branch: x -> out (= x + attn(ln1(x))) ----
  for (int s = 0; s < nA; ++s){
    long r0 = (long)s*Sa;
    gemm_kernel<192,3,1,0><<<dim3(1, Sa/128), 512, 0, stream>>>(
        x, 192, r0, wt_qkv, ln1_g, ln1_b, qkv_b, nullptr, buf, 576, rowmap);
    attn_kernel<<<(int)(Sa/49)*6, 64, 0, stream>>>(buf, bm, r0/49);
    gemm_kernel<192,1,0,1><<<dim3(1, Sa/128), 512, 0, stream>>>(
        buf, 576, r0, wt_proj, nullptr, nullptr, proj_b, x, out, 192, rowmap);
  }

  // ---- MLP branch: out -> out (= x2 + mlp(ln2(x2))) ----
  for (int s = 0; s < nM; ++s){
    long r0 = (long)s*Sm;
    gemm_kernel<192,2,2,2><<<dim3(2, Sm/128), 512, 0, stream>>>(
        out, 192, r0, wt_m1, ln2_g, ln2_b, b1, nullptr, buf, 768, rowmap);
    gemm_kernel<768,1,0,3><<<dim3(1, Sm/128), 512, 0, stream>>>(
        buf, 768, r0, wt_m2, nullptr, nullptr, b2, out, out, 192, rowmap);
  }
}